// Round 3
// baseline (8054.656 us; speedup 1.0000x reference)
//
#include <hip/hip_runtime.h>

typedef unsigned int u32;
typedef unsigned long long u64;
typedef unsigned short u16;

#define DEV __device__ __forceinline__

// exact (x*x + y*y) + z*z, no contraction — must match np elementwise square+sum
DEV float sq3(float x, float y, float z) {
#pragma clang fp contract(off)
  return (x * x + y * y) + z * z;
}
// exact (|q|^2 + |p|^2) - 2*((qx*px + qy*py) + qz*pz), no contraction
DEV float knn_sqd(float4 Q, float4 p) {
#pragma clang fp contract(off)
  float dot = (Q.x * p.x + Q.y * p.y) + Q.z * p.z;
  return (Q.w + p.w) - 2.0f * dot;
}

// ---------- weight table (f32, consolidated once per call) ----------
enum : int {
  W_PEW1 = 0,
  W_PEB1 = 192,
  W_BNG  = 256,
  W_BNB  = 320,
  W_PEW2 = 384,
  W_PEB2 = 8576,
  W_INW  = 8704,    // [2][384][128]
  W_INB  = 107008,  // [2][384]
  W_OUTW = 107776,  // [2][128][128]
  W_OUTB = 140544,  // [2][128]
  W_LN1G = 140800,
  W_LN1B = 141056,
  W_LN2G = 141312,
  W_LN2B = 141568,
  W_FF1W = 141824,  // [2][256][128]
  W_FF1B = 207360,  // [2][256]
  W_FF2W = 207872,  // [2][128][256]
  W_FF2B = 273408,  // [2][128]
  W_FCW  = 273664,  // [256][128]
  W_FCB  = 306432,  // [256]
  W_TOTAL = 306688
};

// compact ws layout (bytes) — mandatory total 2,930,688 B (~2.8 MB)
static const size_t OFF_XYZW  = 1226752;  // [8*4096] float4 (x,y,z,|p|^2)
static const size_t OFF_NEWX  = 1751040;  // [8*1024] float4
static const size_t OFF_KNN   = 1882112;  // [8192*32] int
static const size_t OFF_FEATT = 2930688;  // OPTIONAL [8][4096][128] f32 (16,777,216 B)
static const size_t END_BIG   = 19707904;

struct WArgs { const float* p[20]; };

__global__ void k_convw(WArgs a, float* __restrict__ wf) {
  const int idx = blockIdx.x * 256 + threadIdx.x;
  if (idx >= W_TOTAL) return;
  const int sz[20] = {192, 64, 64, 64, 8192, 128, 98304, 768, 32768, 256,
                      256, 256, 256, 256, 65536, 512, 65536, 256, 32768, 256};
  int rem = idx;
#pragma unroll
  for (int s = 0; s < 20; ++s) {
    if (rem < sz[s]) { wf[idx] = a.p[s][rem]; return; }
    rem -= sz[s];
  }
}

// xyz [B][3][N] f32 -> xyzw [B*N] float4 (x,y,z,sq)
__global__ void k_xyzw(const float* __restrict__ xyz, float4* __restrict__ xyzw) {
  const int i = blockIdx.x * 256 + threadIdx.x;  // 32768 total
  const int b = i >> 12, n = i & 4095;
  const size_t s = (size_t)b * 12288 + n;
  float x = xyz[s];
  float y = xyz[s + 4096];
  float z = xyz[s + 8192];
  xyzw[i] = make_float4(x, y, z, sq3(x, y, z));
}

// features [B][128][4096] f32 -> featT [B][4096][128] f32 (optional path)
__global__ void k_featT(const float* __restrict__ feat, float* __restrict__ featT) {
  __shared__ float tile[32][33];
  const int b = blockIdx.z;
  const int n0 = blockIdx.x << 5, c0 = blockIdx.y << 5;
  const int tx = threadIdx.x, ty = threadIdx.y;  // (32,8)
#pragma unroll
  for (int i = 0; i < 4; ++i) {
    const int c = c0 + ty + (i << 3);
    tile[ty + (i << 3)][tx] = feat[(size_t)b * 524288 + (size_t)c * 4096 + n0 + tx];
  }
  __syncthreads();
#pragma unroll
  for (int i = 0; i < 4; ++i) {
    const int n = n0 + ty + (i << 3);
    featT[(size_t)b * 524288 + (size_t)n * 128 + c0 + tx] = tile[tx][ty + (i << 3)];
  }
}

// ---------- FPS: exact replica of reference scan; 1 block per batch ----------
__global__ __launch_bounds__(256, 1) void k_fps(
    const float4* __restrict__ xyzw, float4* __restrict__ new_xyzw,
    float* __restrict__ out_xyz) {
  __shared__ float PXs[4096], PYs[4096], PZs[4096];
  __shared__ u64 wk[4];
  const int b = blockIdx.x, tid = threadIdx.x;
  const float4* src = xyzw + (size_t)b * 4096;
  float px[16], py[16], pz[16], dm[16];
#pragma unroll
  for (int j = 0; j < 16; ++j) {
    float4 v = src[tid * 16 + j];
    PXs[tid * 16 + j] = v.x; PYs[tid * 16 + j] = v.y; PZs[tid * 16 + j] = v.z;
    px[j] = v.x; py[j] = v.y; pz[j] = v.z; dm[j] = 1e10f;
  }
  __syncthreads();
  float cx = PXs[0], cy = PYs[0], cz = PZs[0];
  if (tid == 0) {
    new_xyzw[(size_t)b * 1024] = make_float4(cx, cy, cz, sq3(cx, cy, cz));
    out_xyz[b * 3072]        = cx;
    out_xyz[b * 3072 + 1024] = cy;
    out_xyz[b * 3072 + 2048] = cz;
  }
  for (int t = 1; t < 1024; ++t) {
    {
      float dx = px[0] - cx, dy = py[0] - cy, dz = pz[0] - cz;
      dm[0] = fminf(dm[0], sq3(dx, dy, dz));
    }
    float bv = dm[0];
    int bi = tid * 16;
#pragma unroll
    for (int j = 1; j < 16; ++j) {
      float dx = px[j] - cx, dy = py[j] - cy, dz = pz[j] - cz;
      float d = sq3(dx, dy, dz);
      dm[j] = fminf(dm[j], d);
      if (dm[j] > bv) { bv = dm[j]; bi = tid * 16 + j; }  // strict > keeps lowest idx
    }
    // key: larger dist wins; equal dist -> smaller index wins
    u64 key = ((u64)__float_as_uint(bv) << 12) | (u32)(4095 - bi);
#pragma unroll
    for (int m = 1; m < 64; m <<= 1) {
      u64 o = __shfl_xor(key, m);
      key = (o > key) ? o : key;
    }
    if ((tid & 63) == 0) wk[tid >> 6] = key;
    __syncthreads();
    u64 ka = wk[0] > wk[1] ? wk[0] : wk[1];
    u64 kb = wk[2] > wk[3] ? wk[2] : wk[3];
    key = ka > kb ? ka : kb;
    const int win = 4095 - (int)(key & 0xfffu);
    cx = PXs[win]; cy = PYs[win]; cz = PZs[win];
    if (tid == 0) {
      new_xyzw[(size_t)b * 1024 + t] = make_float4(cx, cy, cz, sq3(cx, cy, cz));
      out_xyz[b * 3072 + t]        = cx;
      out_xyz[b * 3072 + 1024 + t] = cy;
      out_xyz[b * 3072 + 2048 + t] = cz;
    }
    __syncthreads();
  }
}

// ---------- KNN: exact top-32 (stable ascending), 16 queries/block, 8 thr/query ----------
__global__ __launch_bounds__(128, 1) void k_knn(
    const float4* __restrict__ xyzw, const float4* __restrict__ qxyzw,
    int* __restrict__ knn) {
  __shared__ u64 LL[32 * 128];  // [slot][tid]
  __shared__ int HH[16][8];
  const int tid = threadIdx.x;
  const int ql = tid >> 3, ss = tid & 7;
  const int b = blockIdx.x >> 6;
  const int q = ((blockIdx.x & 63) << 4) + ql;
  const float4 Q = qxyzw[(size_t)b * 1024 + q];
#pragma unroll
  for (int i = 0; i < 32; ++i) LL[i * 128 + tid] = ~0ULL;
  u64 worst = ~0ULL;
  const float4* P = xyzw + (size_t)b * 4096;
  for (int j = 0; j < 512; ++j) {
    const int n = j * 8 + ss;
    float4 p = P[n];
    float sqd = knn_sqd(Q, p);
    u32 u = __float_as_uint(sqd);
    u ^= (u32)((int)u >> 31) | 0x80000000u;  // total-order transform (handles negatives)
    u64 key = ((u64)u << 12) | (u32)n;
    if (key < worst) {
      int pos = 31;
      while (pos > 0 && LL[(pos - 1) * 128 + tid] > key) {
        LL[pos * 128 + tid] = LL[(pos - 1) * 128 + tid];
        --pos;
      }
      LL[pos * 128 + tid] = key;
      worst = LL[31 * 128 + tid];
    }
  }
  __syncthreads();
  if (ss == 0) {
#pragma unroll
    for (int t2 = 0; t2 < 8; ++t2) HH[ql][t2] = 0;
    const size_t ob = ((size_t)b * 1024 + q) * 32;
    for (int o = 0; o < 32; ++o) {
      u64 best = ~0ULL;
      int bs = 0;
#pragma unroll
      for (int t2 = 0; t2 < 8; ++t2) {
        int hh = HH[ql][t2];
        u64 v = (hh < 32) ? LL[hh * 128 + (ql * 8 + t2)] : ~0ULL;
        if (v < best) { best = v; bs = t2; }
      }
      HH[ql][bs]++;
      knn[ob + o] = (int)(best & 0xfffu);
    }
  }
}

// ---------- fused per-group: gather + PE + 2-layer transformer + pool + fc ----------
DEV void ln32(const float* __restrict__ src, float* __restrict__ dst,
              const float* __restrict__ gp, const float* __restrict__ bp, int tid) {
  const int r = tid >> 3, sub = tid & 7;
  const float* row = src + r * 128;
  float4 v[4];
  float s = 0.f;
#pragma unroll
  for (int j = 0; j < 4; ++j) {
    v[j] = *(const float4*)&row[sub * 16 + j * 4];
    s += (v[j].x + v[j].y) + (v[j].z + v[j].w);
  }
  s += __shfl_xor(s, 1); s += __shfl_xor(s, 2); s += __shfl_xor(s, 4);
  const float m = s * 0.0078125f;
  float qv = 0.f;
#pragma unroll
  for (int j = 0; j < 4; ++j) {
    float a = v[j].x - m, b = v[j].y - m, c = v[j].z - m, d = v[j].w - m;
    qv += (a * a + b * b) + (c * c + d * d);
  }
  qv += __shfl_xor(qv, 1); qv += __shfl_xor(qv, 2); qv += __shfl_xor(qv, 4);
  const float rstd = 1.0f / sqrtf(qv * 0.0078125f + 1e-5f);
#pragma unroll
  for (int j = 0; j < 4; ++j) {
    const int c0 = sub * 16 + j * 4;
    float4 g4 = *(const float4*)&gp[c0];
    float4 b4 = *(const float4*)&bp[c0];
    float* d0 = &dst[r * 128 + c0];
    d0[0] = (v[j].x - m) * rstd * g4.x + b4.x;
    d0[1] = (v[j].y - m) * rstd * g4.y + b4.y;
    d0[2] = (v[j].z - m) * rstd * g4.z + b4.z;
    d0[3] = (v[j].w - m) * rstd * g4.w + b4.w;
  }
}

// OUT[r][o] = sum_c IN[r][c] * Wp[o][c] (+bias); 64 col-threads x 4 row-threads
template <int K, int INS, int N, bool RELU, bool ACCUM>
DEV void gemm(const float* __restrict__ IN, const float* __restrict__ Wp,
              const float* __restrict__ bias, float* __restrict__ OUT, int tid) {
  constexpr int NC = N / 64;
  const int oc = tid & 63, rt = tid >> 6;
  float acc[8][NC];
#pragma unroll
  for (int i = 0; i < 8; ++i)
#pragma unroll
    for (int j = 0; j < NC; ++j) acc[i][j] = 0.f;
#pragma unroll 2
  for (int c = 0; c < K; c += 4) {
    float4 w[NC];
#pragma unroll
    for (int j = 0; j < NC; ++j)
      w[j] = *(const float4*)&Wp[(size_t)(oc + 64 * j) * K + c];
#pragma unroll
    for (int i = 0; i < 8; ++i) {
      float4 x = *(const float4*)&IN[(rt * 8 + i) * INS + c];
#pragma unroll
      for (int j = 0; j < NC; ++j)
        acc[i][j] += (x.x * w[j].x + x.y * w[j].y) + (x.z * w[j].z + x.w * w[j].w);
    }
  }
#pragma unroll
  for (int i = 0; i < 8; ++i) {
    const int r = rt * 8 + i;
#pragma unroll
    for (int j = 0; j < NC; ++j) {
      const int o = oc + 64 * j;
      float val = acc[i][j] + bias[o];
      if (RELU) val = fmaxf(val, 0.f);
      if (ACCUM) OUT[r * 128 + o] += val;
      else OUT[r * N + o] = val;
    }
  }
}

__global__ __launch_bounds__(256, 1) void k_xform(
    const float* __restrict__ feat, const float* __restrict__ featT, const int useT,
    const float4* __restrict__ xyzw, const int* __restrict__ knn,
    const float* __restrict__ wf, float* __restrict__ out) {
  __shared__ float X[32 * 128];  // residual
  __shared__ float T[32 * 128];  // h / LN out / scores / pooled
  __shared__ float Y[32 * 384];  // w2 / qkv / ff1
  __shared__ float4 GX[32];
  const int g = blockIdx.x, b = g >> 10, tid = threadIdx.x;
  const int r = tid >> 3, cs = (tid & 7) * 16;
  const int n = knn[g * 32 + r];
  if (tid < 32) GX[tid] = xyzw[(size_t)b * 4096 + knn[g * 32 + tid]];
  // stage pe_w2 [128][64] into Y
  for (int i = tid; i < 8192; i += 256) Y[i] = wf[W_PEW2 + i];
  // gather features -> X
  if (useT) {
    const float* srcp = featT + ((size_t)(b * 4096 + n)) * 128 + cs;
    float* dst = &X[r * 128 + cs];
#pragma unroll
    for (int j = 0; j < 16; j += 4) *(float4*)&dst[j] = *(const float4*)&srcp[j];
  } else {
    const size_t fb0 = (size_t)b * 524288 + n;
    float* dst = &X[r * 128 + cs];
#pragma unroll
    for (int j = 0; j < 16; ++j)
      dst[j] = feat[fb0 + (size_t)(cs + j) * 4096];
  }
  __syncthreads();
  // h = relu(bn(gxyz @ w1.T + b1)) -> T[32][64]
  {
    const int p = tid >> 3, h0 = (tid & 7) * 8;
    float4 g4 = GX[p];
    const float rs = 1.0f / sqrtf(1.0f + 1e-5f);
#pragma unroll
    for (int j = 0; j < 8; ++j) {
      const int c = h0 + j;
      float hv = g4.x * wf[W_PEW1 + c * 3] + g4.y * wf[W_PEW1 + c * 3 + 1] +
                 g4.z * wf[W_PEW1 + c * 3 + 2] + wf[W_PEB1 + c];
      hv = hv * (wf[W_BNG + c] * rs) + wf[W_BNB + c];
      T[p * 64 + c] = fmaxf(hv, 0.f);
    }
  }
  __syncthreads();
  // X += h @ w2.T + b2
  {
    const float* hrow = &T[r * 64];
#pragma unroll 4
    for (int j = 0; j < 16; ++j) {
      const int c = cs + j;
      float acc = wf[W_PEB2 + c];
      const float* wrow = &Y[c * 64];
#pragma unroll
      for (int k = 0; k < 64; k += 4) {
        float4 h4 = *(const float4*)&hrow[k];
        float4 w4 = *(const float4*)&wrow[k];
        acc += (h4.x * w4.x + h4.y * w4.y) + (h4.z * w4.z + h4.w * w4.w);
      }
      X[r * 128 + c] += acc;
    }
  }
  __syncthreads();
  const float scale = 1.0f / sqrtf(32.0f);
#pragma unroll 1
  for (int l = 0; l < 2; ++l) {
    ln32(X, T, wf + W_LN1G + l * 128, wf + W_LN1B + l * 128, tid);
    __syncthreads();
    gemm<128, 128, 384, false, false>(T, wf + W_INW + l * 49152, wf + W_INB + l * 384, Y, tid);
    __syncthreads();
    for (int h = 0; h < 4; ++h) {
      {  // scores -> T[0..1023]
        const int i = tid >> 3, j0 = (tid & 7) * 4;
        const float* qi = &Y[i * 384 + h * 32];
        float a[4] = {0.f, 0.f, 0.f, 0.f};
#pragma unroll
        for (int d = 0; d < 32; d += 4) {
          float4 q4 = *(const float4*)&qi[d];
#pragma unroll
          for (int jj = 0; jj < 4; ++jj) {
            float4 k4 = *(const float4*)&Y[(j0 + jj) * 384 + 128 + h * 32 + d];
            a[jj] += (q4.x * k4.x + q4.y * k4.y) + (q4.z * k4.z + q4.w * k4.w);
          }
        }
#pragma unroll
        for (int jj = 0; jj < 4; ++jj) T[i * 32 + j0 + jj] = a[jj] * scale;
      }
      __syncthreads();
      {  // softmax rows (8 threads/row)
        const int i = tid >> 3, sub = tid & 7;
        float4 v = *(const float4*)&T[i * 32 + sub * 4];
        float mx = fmaxf(fmaxf(v.x, v.y), fmaxf(v.z, v.w));
        mx = fmaxf(mx, __shfl_xor(mx, 1));
        mx = fmaxf(mx, __shfl_xor(mx, 2));
        mx = fmaxf(mx, __shfl_xor(mx, 4));
        float e0 = __expf(v.x - mx), e1 = __expf(v.y - mx);
        float e2 = __expf(v.z - mx), e3 = __expf(v.w - mx);
        float s = (e0 + e1) + (e2 + e3);
        s += __shfl_xor(s, 1); s += __shfl_xor(s, 2); s += __shfl_xor(s, 4);
        const float inv = 1.0f / s;
        *(float4*)&T[i * 32 + sub * 4] = make_float4(e0 * inv, e1 * inv, e2 * inv, e3 * inv);
      }
      __syncthreads();
      {  // av -> write into q-slice of head h (q no longer needed)
        const int i = tid >> 3, d0 = (tid & 7) * 4;
        float a0 = 0.f, a1 = 0.f, a2 = 0.f, a3 = 0.f;
        const float* pr = &T[i * 32];
#pragma unroll 8
        for (int j = 0; j < 32; ++j) {
          const float p = pr[j];
          float4 v4 = *(const float4*)&Y[j * 384 + 256 + h * 32 + d0];
          a0 += p * v4.x; a1 += p * v4.y; a2 += p * v4.z; a3 += p * v4.w;
        }
        *(float4*)&Y[i * 384 + h * 32 + d0] = make_float4(a0, a1, a2, a3);
      }
      __syncthreads();
    }
    // x += attn_out @ W_out^T + b   (attn_out = Y cols 0..127, stride 384)
    gemm<128, 384, 128, false, true>(Y, wf + W_OUTW + l * 16384, wf + W_OUTB + l * 128, X, tid);
    __syncthreads();
    ln32(X, T, wf + W_LN2G + l * 128, wf + W_LN2B + l * 128, tid);
    __syncthreads();
    gemm<128, 128, 256, true, false>(T, wf + W_FF1W + l * 32768, wf + W_FF1B + l * 256, Y, tid);
    __syncthreads();
    gemm<256, 256, 128, false, true>(Y, wf + W_FF2W + l * 32768, wf + W_FF2B + l * 128, X, tid);
    __syncthreads();
  }
  // pool -> T[0..127]
  if (tid < 128) {
    float m = X[tid];
#pragma unroll
    for (int rr = 1; rr < 32; ++rr) m = fmaxf(m, X[rr * 128 + tid]);
    T[tid] = m;
  }
  __syncthreads();
  // fc: one output channel per thread
  {
    float acc = wf[W_FCB + tid];
    const float* wr = wf + W_FCW + tid * 128;
#pragma unroll 8
    for (int c = 0; c < 128; c += 4) {
      float4 w4 = *(const float4*)&wr[c];
      float4 x4 = *(const float4*)&T[c];
      acc += (x4.x * w4.x + x4.y * w4.y) + (x4.z * w4.z + x4.w * w4.w);
    }
    const int s = g & 1023;
    out[24576 + (size_t)b * 262144 + (size_t)tid * 1024 + s] = acc;
  }
}

extern "C" void kernel_launch(void* const* d_in, const int* in_sizes, int n_in,
                              void* d_out, int out_size, void* d_ws, size_t ws_size,
                              hipStream_t stream) {
  (void)in_sizes; (void)n_in; (void)out_size;
  char* ws = (char*)d_ws;
  float* wf    = (float*)ws;
  float4* xyzw = (float4*)(ws + OFF_XYZW);
  float4* newx = (float4*)(ws + OFF_NEWX);
  int* knni    = (int*)(ws + OFF_KNN);
  const float* xyz  = (const float*)d_in[0];
  const float* feat = (const float*)d_in[1];
  const int useT = (ws_size >= END_BIG) ? 1 : 0;
  float* featT = useT ? (float*)(ws + OFF_FEATT) : (float*)d_in[1];  // dummy ptr when unused
  WArgs wa;
  for (int i = 0; i < 20; ++i) wa.p[i] = (const float*)d_in[2 + i];
  float* outp = (float*)d_out;

  hipLaunchKernelGGL(k_convw, dim3(1198), dim3(256), 0, stream, wa, wf);
  hipLaunchKernelGGL(k_xyzw, dim3(128), dim3(256), 0, stream, xyz, xyzw);
  if (useT)
    hipLaunchKernelGGL(k_featT, dim3(128, 4, 8), dim3(32, 8), 0, stream, feat, featT);
  hipLaunchKernelGGL(k_fps, dim3(8), dim3(256), 0, stream, xyzw, newx, outp);
  hipLaunchKernelGGL(k_knn, dim3(512), dim3(128), 0, stream, xyzw, newx, knni);
  hipLaunchKernelGGL(k_xform, dim3(8192), dim3(256), 0, stream,
                     feat, featT, useT, xyzw, knni, wf, outp);
}

// Round 4
// 5768.016 us; speedup vs baseline: 1.3964x; 1.3964x over previous
//
#include <hip/hip_runtime.h>

typedef unsigned int u32;
typedef unsigned long long u64;
typedef unsigned short u16;

#define DEV __device__ __forceinline__

// exact (x*x + y*y) + z*z, no contraction — must match np elementwise square+sum
DEV float sq3(float x, float y, float z) {
#pragma clang fp contract(off)
  return (x * x + y * y) + z * z;
}
// exact (|q|^2 + |p|^2) - 2*((qx*px + qy*py) + qz*pz), no contraction
DEV float knn_sqd(float4 Q, float4 p) {
#pragma clang fp contract(off)
  float dot = (Q.x * p.x + Q.y * p.y) + Q.z * p.z;
  return (Q.w + p.w) - 2.0f * dot;
}
DEV float dot4(float4 a, float4 b) {
  return (a.x * b.x + a.y * b.y) + (a.z * b.z + a.w * b.w);
}

// ---------- weight table (f32, consolidated once per call) ----------
enum : int {
  W_PEW1 = 0,
  W_PEB1 = 192,
  W_BNG  = 256,
  W_BNB  = 320,
  W_PEW2 = 384,
  W_PEB2 = 8576,
  W_INW  = 8704,    // [2][384][128]
  W_INB  = 107008,  // [2][384]
  W_OUTW = 107776,  // [2][128][128]
  W_OUTB = 140544,  // [2][128]
  W_LN1G = 140800,
  W_LN1B = 141056,
  W_LN2G = 141312,
  W_LN2B = 141568,
  W_FF1W = 141824,  // [2][256][128]
  W_FF1B = 207360,  // [2][256]
  W_FF2W = 207872,  // [2][128][256]
  W_FF2B = 273408,  // [2][128]
  W_FCW  = 273664,  // [256][128]
  W_FCB  = 306432,  // [256]
  W_TOTAL = 306688
};

// precomputed-weight region (float offsets inside wp)
enum : int {
  WP_QW = 0,       // [2][384][128] g-folded qkv weights
  WP_QB = 98304,   // [2][384] folded bias
  WP_FW = 99072,   // [2][256][128] g-folded ff1 weights
  WP_FB = 164608,  // [2][256]
  WP_TOTAL = 165120
};

// ws byte offsets — mandatory total 3,591,168 B (~3.4 MB)
static const size_t OFF_XYZW  = 1226752;  // [8*4096] float4 (x,y,z,|p|^2)
static const size_t OFF_NEWX  = 1751040;  // [8*1024] float4
static const size_t OFF_KNN   = 1882112;  // [8192*32] int
static const size_t OFF_WP    = 2930688;  // [165120] float
static const size_t OFF_FEATT = 3591168;  // OPTIONAL [8][4096][128] f32 (16,777,216 B)
static const size_t END_BIG   = 20368384;

struct WArgs { const float* p[20]; };

__global__ void k_convw(WArgs a, float* __restrict__ wf) {
  const int idx = blockIdx.x * 256 + threadIdx.x;
  if (idx >= W_TOTAL) return;
  const int sz[20] = {192, 64, 64, 64, 8192, 128, 98304, 768, 32768, 256,
                      256, 256, 256, 256, 65536, 512, 65536, 256, 32768, 256};
  int rem = idx;
#pragma unroll
  for (int s = 0; s < 20; ++s) {
    if (rem < sz[s]) { wf[idx] = a.p[s][rem]; return; }
    rem -= sz[s];
  }
}

// fold LN gamma into qkv/ff1 weights; fold LN beta into their biases
__global__ void k_prep(const float* __restrict__ wf, float* __restrict__ wp) {
  const int idx = blockIdx.x * 256 + threadIdx.x;
  if (idx >= 1280) return;
  const float *W, *G, *Bln, *B0;
  float *WO, *BO;
  if (idx < 768) {
    const int l = idx / 384, o = idx % 384;
    W = wf + W_INW + l * 49152 + o * 128;
    G = wf + W_LN1G + l * 128; Bln = wf + W_LN1B + l * 128;
    B0 = wf + W_INB + l * 384 + o;
    WO = wp + WP_QW + l * 49152 + o * 128;
    BO = wp + WP_QB + l * 384 + o;
  } else {
    const int j2 = idx - 768, l = j2 / 256, o = j2 % 256;
    W = wf + W_FF1W + l * 32768 + o * 128;
    G = wf + W_LN2G + l * 128; Bln = wf + W_LN2B + l * 128;
    B0 = wf + W_FF1B + l * 256 + o;
    WO = wp + WP_FW + l * 32768 + o * 128;
    BO = wp + WP_FB + l * 256 + o;
  }
  float acc = *B0;
  for (int c = 0; c < 128; ++c) {
    const float w = W[c];
    WO[c] = w * G[c];
    acc += Bln[c] * w;
  }
  *BO = acc;
}

// xyz [B][3][N] f32 -> xyzw [B*N] float4 (x,y,z,sq)
__global__ void k_xyzw(const float* __restrict__ xyz, float4* __restrict__ xyzw) {
  const int i = blockIdx.x * 256 + threadIdx.x;  // 32768 total
  const int b = i >> 12, n = i & 4095;
  const size_t s = (size_t)b * 12288 + n;
  float x = xyz[s];
  float y = xyz[s + 4096];
  float z = xyz[s + 8192];
  xyzw[i] = make_float4(x, y, z, sq3(x, y, z));
}

// ---------- fused: blocks 0..7 = FPS (serial scan); blocks 8.. = feature transpose ----------
__global__ __launch_bounds__(256, 1) void k_pre(
    const float4* __restrict__ xyzw, float4* __restrict__ new_xyzw,
    float* __restrict__ out_xyz, const float* __restrict__ feat,
    float* __restrict__ featT) {
  __shared__ float PXs[4096], PYs[4096], PZs[4096];
  __shared__ u64 wk[4];
  __shared__ float tile[32][33];
  const int tid = threadIdx.x;
  if (blockIdx.x >= 8) {
    // transpose: features [B][128][4096] -> featT [B][4096][128]
    const int bb = blockIdx.x - 8;
    const int b = bb >> 9, r2 = bb & 511;
    const int n0 = (r2 >> 2) << 5, c0 = (r2 & 3) << 5;
    const int tx = tid & 31, ty = tid >> 5;  // 32 x 8
#pragma unroll
    for (int i = 0; i < 4; ++i) {
      const int c = c0 + ty + (i << 3);
      tile[ty + (i << 3)][tx] = feat[(size_t)b * 524288 + (size_t)c * 4096 + n0 + tx];
    }
    __syncthreads();
#pragma unroll
    for (int i = 0; i < 4; ++i) {
      const int n = n0 + ty + (i << 3);
      featT[(size_t)b * 524288 + (size_t)n * 128 + c0 + tx] = tile[tx][ty + (i << 3)];
    }
    return;
  }
  // FPS — exact replica of reference scan
  const int b = blockIdx.x;
  const float4* src = xyzw + (size_t)b * 4096;
  float px[16], py[16], pz[16], dm[16];
#pragma unroll
  for (int j = 0; j < 16; ++j) {
    float4 v = src[tid * 16 + j];
    PXs[tid * 16 + j] = v.x; PYs[tid * 16 + j] = v.y; PZs[tid * 16 + j] = v.z;
    px[j] = v.x; py[j] = v.y; pz[j] = v.z; dm[j] = 1e10f;
  }
  __syncthreads();
  float cx = PXs[0], cy = PYs[0], cz = PZs[0];
  if (tid == 0) {
    new_xyzw[(size_t)b * 1024] = make_float4(cx, cy, cz, sq3(cx, cy, cz));
    out_xyz[b * 3072]        = cx;
    out_xyz[b * 3072 + 1024] = cy;
    out_xyz[b * 3072 + 2048] = cz;
  }
  for (int t = 1; t < 1024; ++t) {
    {
      float dx = px[0] - cx, dy = py[0] - cy, dz = pz[0] - cz;
      dm[0] = fminf(dm[0], sq3(dx, dy, dz));
    }
    float bv = dm[0];
    int bi = tid * 16;
#pragma unroll
    for (int j = 1; j < 16; ++j) {
      float dx = px[j] - cx, dy = py[j] - cy, dz = pz[j] - cz;
      float d = sq3(dx, dy, dz);
      dm[j] = fminf(dm[j], d);
      if (dm[j] > bv) { bv = dm[j]; bi = tid * 16 + j; }  // strict > keeps lowest idx
    }
    u64 key = ((u64)__float_as_uint(bv) << 12) | (u32)(4095 - bi);
#pragma unroll
    for (int m = 1; m < 64; m <<= 1) {
      u64 o = __shfl_xor(key, m);
      key = (o > key) ? o : key;
    }
    if ((tid & 63) == 0) wk[tid >> 6] = key;
    __syncthreads();
    u64 ka = wk[0] > wk[1] ? wk[0] : wk[1];
    u64 kb = wk[2] > wk[3] ? wk[2] : wk[3];
    key = ka > kb ? ka : kb;
    const int win = 4095 - (int)(key & 0xfffu);
    cx = PXs[win]; cy = PYs[win]; cz = PZs[win];
    if (tid == 0) {
      new_xyzw[(size_t)b * 1024 + t] = make_float4(cx, cy, cz, sq3(cx, cy, cz));
      out_xyz[b * 3072 + t]        = cx;
      out_xyz[b * 3072 + 1024 + t] = cy;
      out_xyz[b * 3072 + 2048 + t] = cz;
    }
    __syncthreads();
  }
}

// ---------- KNN: exact top-32 (stable ascending), 16 queries/block, 8 thr/query ----------
__global__ __launch_bounds__(128, 1) void k_knn(
    const float4* __restrict__ xyzw, const float4* __restrict__ qxyzw,
    int* __restrict__ knn) {
  __shared__ u64 LL[32 * 128];  // [slot][tid]
  __shared__ int HH[16][8];
  const int tid = threadIdx.x;
  const int ql = tid >> 3, ss = tid & 7;
  const int b = blockIdx.x >> 6;
  const int q = ((blockIdx.x & 63) << 4) + ql;
  const float4 Q = qxyzw[(size_t)b * 1024 + q];
#pragma unroll
  for (int i = 0; i < 32; ++i) LL[i * 128 + tid] = ~0ULL;
  u64 worst = ~0ULL;
  const float4* P = xyzw + (size_t)b * 4096;
  for (int j = 0; j < 512; ++j) {
    const int n = j * 8 + ss;
    float4 p = P[n];
    float sqd = knn_sqd(Q, p);
    u32 u = __float_as_uint(sqd);
    u ^= (u32)((int)u >> 31) | 0x80000000u;  // total-order transform
    u64 key = ((u64)u << 12) | (u32)n;
    if (key < worst) {
      int pos = 31;
      while (pos > 0 && LL[(pos - 1) * 128 + tid] > key) {
        LL[pos * 128 + tid] = LL[(pos - 1) * 128 + tid];
        --pos;
      }
      LL[pos * 128 + tid] = key;
      worst = LL[31 * 128 + tid];
    }
  }
  __syncthreads();
  if (ss == 0) {
#pragma unroll
    for (int t2 = 0; t2 < 8; ++t2) HH[ql][t2] = 0;
    const size_t ob = ((size_t)b * 1024 + q) * 32;
    for (int o = 0; o < 32; ++o) {
      u64 best = ~0ULL;
      int bs = 0;
#pragma unroll
      for (int t2 = 0; t2 < 8; ++t2) {
        int hh = HH[ql][t2];
        u64 v = (hh < 32) ? LL[hh * 128 + (ql * 8 + t2)] : ~0ULL;
        if (v < best) { best = v; bs = t2; }
      }
      HH[ql][bs]++;
      knn[ob + o] = (int)(best & 0xfffu);
    }
  }
}

// ---------- fused per-group transformer ----------
// LDS float layout: X[32*132] @0, Yf[12416] @4224, S[1152] @16640, MR[128] @17792,
// GX[32 float4] @17920 — total 18048 floats = 72,192 B -> 2 blocks/CU.

// in-place LN: X <- (x-m)*rstd; MR[r] = {m, rstd, sd}
DEV void ln_statsZ(float* __restrict__ X, float* __restrict__ MR, int tid) {
  const int r = tid >> 3, sub = tid & 7;
  float* row = X + r * 132 + sub * 16;
  float4 v[4];
  float s = 0.f;
#pragma unroll
  for (int j = 0; j < 4; ++j) {
    v[j] = *(const float4*)&row[j * 4];
    s += (v[j].x + v[j].y) + (v[j].z + v[j].w);
  }
  s += __shfl_xor(s, 1); s += __shfl_xor(s, 2); s += __shfl_xor(s, 4);
  const float m = s * 0.0078125f;
  float qv = 0.f;
#pragma unroll
  for (int j = 0; j < 4; ++j) {
    float a = v[j].x - m, b = v[j].y - m, c = v[j].z - m, d = v[j].w - m;
    qv += (a * a + b * b) + (c * c + d * d);
  }
  qv += __shfl_xor(qv, 1); qv += __shfl_xor(qv, 2); qv += __shfl_xor(qv, 4);
  const float sd = sqrtf(qv * 0.0078125f + 1e-5f);
  const float rstd = 1.0f / sd;
#pragma unroll
  for (int j = 0; j < 4; ++j) {
    row[j * 4 + 0] = (v[j].x - m) * rstd;
    row[j * 4 + 1] = (v[j].y - m) * rstd;
    row[j * 4 + 2] = (v[j].z - m) * rstd;
    row[j * 4 + 3] = (v[j].w - m) * rstd;
  }
  if (sub == 0) { MR[r * 4] = m; MR[r * 4 + 1] = rstd; MR[r * 4 + 2] = sd; }
}

// OUT[r][o] = sum_c IN[r][c]*Wp[o][c] + bias[o]
// MODE 0: store; MODE 2: X-recon accumulate: OUT = OUT*sd + m + val
template <int K, int INS, int N, int OUTS, bool RELU, int MODE>
DEV void gemm(const float* __restrict__ IN, const float* __restrict__ Wp,
              const float* __restrict__ bias, float* __restrict__ OUT,
              const float* __restrict__ MR, int tid) {
  constexpr int NC = N / 64;
  const int oc = tid & 63, rt = tid >> 6;
  float acc[8][NC];
#pragma unroll
  for (int i = 0; i < 8; ++i)
#pragma unroll
    for (int j = 0; j < NC; ++j) acc[i][j] = 0.f;
#pragma unroll 2
  for (int c = 0; c < K; c += 4) {
    float4 w[NC];
#pragma unroll
    for (int j = 0; j < NC; ++j)
      w[j] = *(const float4*)&Wp[(size_t)(oc + 64 * j) * K + c];
#pragma unroll
    for (int i = 0; i < 8; ++i) {
      float4 x = *(const float4*)&IN[(rt * 8 + i) * INS + c];
#pragma unroll
      for (int j = 0; j < NC; ++j) acc[i][j] += dot4(x, w[j]);
    }
  }
#pragma unroll
  for (int i = 0; i < 8; ++i) {
    const int r = rt * 8 + i;
    float mm = 0.f, sd = 1.f;
    if (MODE == 2) { mm = MR[r * 4]; sd = MR[r * 4 + 2]; }
#pragma unroll
    for (int j = 0; j < NC; ++j) {
      const int o = oc + 64 * j;
      float val = acc[i][j] + bias[o];
      if (RELU) val = fmaxf(val, 0.f);
      if (MODE == 0) OUT[r * OUTS + o] = val;
      else OUT[r * OUTS + o] = OUT[r * OUTS + o] * sd + mm + val;
    }
  }
}

__global__ __launch_bounds__(256, 2) void k_xform(
    const float* __restrict__ feat, const float* __restrict__ featT, const int useT,
    const float4* __restrict__ xyzw, const int* __restrict__ knn,
    const float* __restrict__ wf, const float* __restrict__ wp,
    float* __restrict__ out) {
  __shared__ __align__(16) float sm[18048];
  float* X  = sm;            // [32][132]
  float* Yf = sm + 4224;     // qkv rows stride 388; PE: w2 rows stride 68 (128 rows), h at +8704
  float* S  = sm + 16640;    // [32][36]
  float* MR = sm + 17792;    // [32][4]
  float4* GX = (float4*)(sm + 17920);
  const int g = blockIdx.x, b = g >> 10, tid = threadIdx.x;
  const int r = tid >> 3, sub = tid & 7, cs = sub * 16;
  const int n = knn[g * 32 + r];
  if (tid < 32) GX[tid] = xyzw[(size_t)b * 4096 + knn[g * 32 + tid]];
  // stage pe_w2 [128][64] -> Yf rows stride 68
  for (int i = tid; i < 8192; i += 256) Yf[(i >> 6) * 68 + (i & 63)] = wf[W_PEW2 + i];
  // gather features -> X
  if (useT) {
    const float* srcp = featT + ((size_t)(b * 4096 + n)) * 128 + cs;
    float* dst = &X[r * 132 + cs];
#pragma unroll
    for (int j = 0; j < 16; j += 4) *(float4*)&dst[j] = *(const float4*)&srcp[j];
  } else {
    const size_t fb0 = (size_t)b * 524288 + n;
    float* dst = &X[r * 132 + cs];
#pragma unroll
    for (int j = 0; j < 16; ++j) dst[j] = feat[fb0 + (size_t)(cs + j) * 4096];
  }
  __syncthreads();
  // h = relu(bn(gxyz @ w1.T + b1)) -> Yf[8704 + p*68 + c]
  {
    const float4 g4 = GX[r];
    const float rs = 1.0f / sqrtf(1.0f + 1e-5f);
#pragma unroll
    for (int jj = 0; jj < 8; ++jj) {
      const int c = sub + 8 * jj;
      float hv = g4.x * wf[W_PEW1 + c * 3] + g4.y * wf[W_PEW1 + c * 3 + 1] +
                 g4.z * wf[W_PEW1 + c * 3 + 2] + wf[W_PEB1 + c];
      hv = hv * (wf[W_BNG + c] * rs) + wf[W_BNB + c];
      Yf[8704 + r * 68 + c] = fmaxf(hv, 0.f);
    }
  }
  __syncthreads();
  // X += h @ w2.T + b2
  {
    const float* hrow = &Yf[8704 + r * 68];
#pragma unroll 4
    for (int j = 0; j < 16; ++j) {
      const int c = sub + 8 * j;
      float acc = wf[W_PEB2 + c];
      const float* wrow = &Yf[c * 68];
#pragma unroll
      for (int k = 0; k < 64; k += 4)
        acc += dot4(*(const float4*)&hrow[k], *(const float4*)&wrow[k]);
      X[r * 132 + c] += acc;
    }
  }
  __syncthreads();
  const float scale = 1.0f / sqrtf(32.0f);
#pragma unroll 1
  for (int l = 0; l < 2; ++l) {
    ln_statsZ(X, MR, tid);
    __syncthreads();
    gemm<128, 132, 384, 388, false, 0>(X, wp + WP_QW + l * 49152, wp + WP_QB + l * 384, Yf, MR, tid);
    __syncthreads();
#pragma unroll 1
    for (int h = 0; h < 4; ++h) {
      {  // scores: lane (r, sub) handles j = sub + 8*jj
        const float* qi = &Yf[r * 388 + h * 32];
        float a[4] = {0.f, 0.f, 0.f, 0.f};
#pragma unroll
        for (int d = 0; d < 32; d += 4) {
          float4 q4 = *(const float4*)&qi[d];
#pragma unroll
          for (int jj = 0; jj < 4; ++jj) {
            float4 k4 = *(const float4*)&Yf[(sub + 8 * jj) * 388 + 128 + h * 32 + d];
            a[jj] += dot4(q4, k4);
          }
        }
#pragma unroll
        for (int jj = 0; jj < 4; ++jj) a[jj] *= scale;
        float mx = fmaxf(fmaxf(a[0], a[1]), fmaxf(a[2], a[3]));
        mx = fmaxf(mx, __shfl_xor(mx, 1));
        mx = fmaxf(mx, __shfl_xor(mx, 2));
        mx = fmaxf(mx, __shfl_xor(mx, 4));
        float e0 = __expf(a[0] - mx), e1 = __expf(a[1] - mx);
        float e2 = __expf(a[2] - mx), e3 = __expf(a[3] - mx);
        float s = (e0 + e1) + (e2 + e3);
        s += __shfl_xor(s, 1); s += __shfl_xor(s, 2); s += __shfl_xor(s, 4);
        const float inv = 1.0f / s;
        S[r * 36 + sub]      = e0 * inv;
        S[r * 36 + sub + 8]  = e1 * inv;
        S[r * 36 + sub + 16] = e2 * inv;
        S[r * 36 + sub + 24] = e3 * inv;
      }
      __syncthreads();
      {  // AV -> q-slice of head h
        const int d0 = sub * 4;
        float a0 = 0.f, a1 = 0.f, a2 = 0.f, a3 = 0.f;
        const float* pr = &S[r * 36];
#pragma unroll 8
        for (int j = 0; j < 32; ++j) {
          const float p = pr[j];
          float4 v4 = *(const float4*)&Yf[j * 388 + 256 + h * 32 + d0];
          a0 += p * v4.x; a1 += p * v4.y; a2 += p * v4.z; a3 += p * v4.w;
        }
        *(float4*)&Yf[r * 388 + h * 32 + d0] = make_float4(a0, a1, a2, a3);
      }
      __syncthreads();
    }
    // x = recon(z) + attn_out @ W_out^T + b
    gemm<128, 388, 128, 132, false, 2>(Yf, wf + W_OUTW + l * 16384, wf + W_OUTB + l * 128, X, MR, tid);
    __syncthreads();
    ln_statsZ(X, MR, tid);
    __syncthreads();
    gemm<128, 132, 256, 388, true, 0>(X, wp + WP_FW + l * 32768, wp + WP_FB + l * 256, Yf, MR, tid);
    __syncthreads();
    gemm<256, 388, 128, 132, false, 2>(Yf, wf + W_FF2W + l * 32768, wf + W_FF2B + l * 128, X, MR, tid);
    __syncthreads();
  }
  // pool -> S[0..127]
  if (tid < 128) {
    float m = X[tid];
#pragma unroll
    for (int rr = 1; rr < 32; ++rr) m = fmaxf(m, X[rr * 132 + tid]);
    S[tid] = m;
  }
  __syncthreads();
  // fc: one output channel per thread
  {
    float acc = wf[W_FCB + tid];
    const float* wr = wf + W_FCW + tid * 128;
#pragma unroll 8
    for (int c = 0; c < 128; c += 4) {
      float4 w4 = *(const float4*)&wr[c];
      float4 x4 = *(const float4*)&S[c];
      acc += dot4(x4, w4);
    }
    const int s = g & 1023;
    out[24576 + (size_t)b * 262144 + (size_t)tid * 1024 + s] = acc;
  }
}

extern "C" void kernel_launch(void* const* d_in, const int* in_sizes, int n_in,
                              void* d_out, int out_size, void* d_ws, size_t ws_size,
                              hipStream_t stream) {
  (void)in_sizes; (void)n_in; (void)out_size;
  char* ws = (char*)d_ws;
  float* wf    = (float*)ws;
  float4* xyzw = (float4*)(ws + OFF_XYZW);
  float4* newx = (float4*)(ws + OFF_NEWX);
  int* knni    = (int*)(ws + OFF_KNN);
  float* wp    = (float*)(ws + OFF_WP);
  const float* xyz  = (const float*)d_in[0];
  const float* feat = (const float*)d_in[1];
  const int useT = (ws_size >= END_BIG) ? 1 : 0;
  float* featT = useT ? (float*)(ws + OFF_FEATT) : (float*)d_in[1];
  WArgs wa;
  for (int i = 0; i < 20; ++i) wa.p[i] = (const float*)d_in[2 + i];
  float* outp = (float*)d_out;

  hipLaunchKernelGGL(k_convw, dim3(1198), dim3(256), 0, stream, wa, wf);
  hipLaunchKernelGGL(k_prep, dim3(5), dim3(256), 0, stream, wf, wp);
  hipLaunchKernelGGL(k_xyzw, dim3(128), dim3(256), 0, stream, xyz, xyzw);
  hipLaunchKernelGGL(k_pre, dim3(useT ? 4104 : 8), dim3(256), 0, stream,
                     xyzw, newx, outp, feat, featT);
  hipLaunchKernelGGL(k_knn, dim3(512), dim3(128), 0, stream, xyzw, newx, knni);
  hipLaunchKernelGGL(k_xform, dim3(8192), dim3(256), 0, stream,
                     feat, featT, useT, xyzw, knni, wf, wp, outp);
}

// Round 5
// 3889.844 us; speedup vs baseline: 2.0707x; 1.4828x over previous
//
#include <hip/hip_runtime.h>

typedef unsigned int u32;
typedef unsigned long long u64;
typedef unsigned short u16;
typedef __attribute__((ext_vector_type(8))) short bf16x8;
typedef __attribute__((ext_vector_type(4))) float f32x4;

#define DEV __device__ __forceinline__

DEV float sq3(float x, float y, float z) {
#pragma clang fp contract(off)
  return (x * x + y * y) + z * z;
}
DEV float knn_sqd(float4 Q, float4 p) {
#pragma clang fp contract(off)
  float dot = (Q.x * p.x + Q.y * p.y) + Q.z * p.z;
  return (Q.w + p.w) - 2.0f * dot;
}
DEV float dot4(float4 a, float4 b) {
  return (a.x * b.x + a.y * b.y) + (a.z * b.z + a.w * b.w);
}
DEV u32 f2bfu(float f) {
  u32 u = __float_as_uint(f);
  return (u + 0x7fffu + ((u >> 16) & 1u)) >> 16;
}
DEV f32x4 MFMA(bf16x8 a, bf16x8 b, f32x4 c) {
  return __builtin_amdgcn_mfma_f32_16x16x32_bf16(a, b, c, 0, 0, 0);
}

// ---------- weight table (f32) ----------
enum : int {
  W_PEW1 = 0, W_PEB1 = 192, W_BNG = 256, W_BNB = 320,
  W_PEW2 = 384, W_PEB2 = 8576,
  W_INW  = 8704,   W_INB  = 107008,
  W_OUTW = 107776, W_OUTB = 140544,
  W_LN1G = 140800, W_LN1B = 141056, W_LN2G = 141312, W_LN2B = 141568,
  W_FF1W = 141824, W_FF1B = 207360,
  W_FF2W = 207872, W_FF2B = 273408,
  W_FCW  = 273664, W_FCB  = 306432,
  W_TOTAL = 306688
};
// folded f32 biases
enum : int { WP_QB = 0, WP_FB = 768, WP_TOTAL = 1280 };
// bf16 weight planes (u16 element offsets)
enum : int {
  WB_QHI = 0,      WB_QLO = 98304,
  WB_OHI = 196608, WB_OLO = 229376,
  WB_F1HI = 262144, WB_F1LO = 327680,
  WB_F2HI = 393216, WB_F2LO = 458752,
  WB_P2HI = 524288, WB_P2LO = 532480,
  WB_TOTAL = 540672
};

// ws byte offsets
static const size_t OFF_XYZW  = 1226752;  // [8*4096] float4
static const size_t OFF_NEWX  = 1751040;  // [8*1024] float4
static const size_t OFF_KNN   = 1882112;  // [8192*32] int
static const size_t OFF_WP    = 2930688;  // WP_TOTAL f32
static const size_t OFF_WB    = 2936064;  // WB_TOTAL u16 (1,081,344 B)
static const size_t OFF_FEATT = 4017408;  // OPTIONAL [8][4096][128] f32
static const size_t END_BIG   = 20794624;

struct WArgs { const float* p[20]; };

__global__ void k_convw(WArgs a, float* __restrict__ wf) {
  const int idx = blockIdx.x * 256 + threadIdx.x;
  if (idx >= W_TOTAL) return;
  const int sz[20] = {192, 64, 64, 64, 8192, 128, 98304, 768, 32768, 256,
                      256, 256, 256, 256, 65536, 512, 65536, 256, 32768, 256};
  int rem = idx;
#pragma unroll
  for (int s = 0; s < 20; ++s) {
    if (rem < sz[s]) { wf[idx] = a.p[s][rem]; return; }
    rem -= sz[s];
  }
}

DEV void splitst(float w, u16* ph, u16* pl) {
  u32 h = __float_as_uint(w) >> 16;
  *ph = (u16)h;
  *pl = (u16)f2bfu(w - __uint_as_float(h << 16));
}

// fold LN gamma/beta into qkv/ff1; emit bf16 hi/lo planes for all big GEMMs
__global__ void k_prep(const float* __restrict__ wf, float* __restrict__ wp,
                       u16* __restrict__ wb) {
  const int idx = blockIdx.x * 256 + threadIdx.x;
  if (idx >= 1920) return;
  if (idx < 768) {  // qkv
    const int l = idx / 384, o = idx % 384;
    const float* W = wf + W_INW + l * 49152 + o * 128;
    const float* G = wf + W_LN1G + l * 128;
    const float* Bl = wf + W_LN1B + l * 128;
    float acc = wf[W_INB + l * 384 + o];
    u16* ph = wb + WB_QHI + (l * 384 + o) * 128;
    u16* pl = wb + WB_QLO + (l * 384 + o) * 128;
    for (int c = 0; c < 128; ++c) {
      const float w = W[c];
      acc += Bl[c] * w;
      splitst(w * G[c], ph + c, pl + c);
    }
    wp[WP_QB + l * 384 + o] = acc;
  } else if (idx < 1280) {  // ff1
    const int j2 = idx - 768, l = j2 / 256, o = j2 % 256;
    const float* W = wf + W_FF1W + l * 32768 + o * 128;
    const float* G = wf + W_LN2G + l * 128;
    const float* Bl = wf + W_LN2B + l * 128;
    float acc = wf[W_FF1B + l * 256 + o];
    u16* ph = wb + WB_F1HI + (l * 256 + o) * 128;
    u16* pl = wb + WB_F1LO + (l * 256 + o) * 128;
    for (int c = 0; c < 128; ++c) {
      const float w = W[c];
      acc += Bl[c] * w;
      splitst(w * G[c], ph + c, pl + c);
    }
    wp[WP_FB + l * 256 + o] = acc;
  } else if (idx < 1536) {  // out-proj
    const int j2 = idx - 1280, l = j2 / 128, o = j2 % 128;
    const float* W = wf + W_OUTW + l * 16384 + o * 128;
    u16* ph = wb + WB_OHI + (l * 128 + o) * 128;
    u16* pl = wb + WB_OLO + (l * 128 + o) * 128;
    for (int c = 0; c < 128; ++c) splitst(W[c], ph + c, pl + c);
  } else if (idx < 1792) {  // ff2 (K=256)
    const int j2 = idx - 1536, l = j2 / 128, o = j2 % 128;
    const float* W = wf + W_FF2W + l * 32768 + o * 256;
    u16* ph = wb + WB_F2HI + (l * 128 + o) * 256;
    u16* pl = wb + WB_F2LO + (l * 128 + o) * 256;
    for (int c = 0; c < 256; ++c) splitst(W[c], ph + c, pl + c);
  } else {  // pe_w2 (K=64)
    const int o = idx - 1792;
    const float* W = wf + W_PEW2 + o * 64;
    u16* ph = wb + WB_P2HI + o * 64;
    u16* pl = wb + WB_P2LO + o * 64;
    for (int c = 0; c < 64; ++c) splitst(W[c], ph + c, pl + c);
  }
}

// xyz [B][3][N] f32 -> xyzw [B*N] float4 (x,y,z,sq)
__global__ void k_xyzw(const float* __restrict__ xyz, float4* __restrict__ xyzw) {
  const int i = blockIdx.x * 256 + threadIdx.x;
  const int b = i >> 12, n = i & 4095;
  const size_t s = (size_t)b * 12288 + n;
  float x = xyz[s], y = xyz[s + 4096], z = xyz[s + 8192];
  xyzw[i] = make_float4(x, y, z, sq3(x, y, z));
}

// ---------- fused: blocks 0..7 = FPS; blocks 8.. = feature transpose ----------
__global__ __launch_bounds__(256, 1) void k_pre(
    const float4* __restrict__ xyzw, float4* __restrict__ new_xyzw,
    float* __restrict__ out_xyz, const float* __restrict__ feat,
    float* __restrict__ featT) {
  __shared__ float PXs[4096], PYs[4096], PZs[4096];
  __shared__ u64 wk[4];
  __shared__ float tile[32][33];
  const int tid = threadIdx.x;
  if (blockIdx.x >= 8) {
    const int bb = blockIdx.x - 8;
    const int b = bb >> 9, r2 = bb & 511;
    const int n0 = (r2 >> 2) << 5, c0 = (r2 & 3) << 5;
    const int tx = tid & 31, ty = tid >> 5;
#pragma unroll
    for (int i = 0; i < 4; ++i) {
      const int c = c0 + ty + (i << 3);
      tile[ty + (i << 3)][tx] = feat[(size_t)b * 524288 + (size_t)c * 4096 + n0 + tx];
    }
    __syncthreads();
#pragma unroll
    for (int i = 0; i < 4; ++i) {
      const int n = n0 + ty + (i << 3);
      featT[(size_t)b * 524288 + (size_t)n * 128 + c0 + tx] = tile[tx][ty + (i << 3)];
    }
    return;
  }
  const int b = blockIdx.x;
  const float4* src = xyzw + (size_t)b * 4096;
  float px[16], py[16], pz[16], dm[16];
#pragma unroll
  for (int j = 0; j < 16; ++j) {
    float4 v = src[tid * 16 + j];
    PXs[tid * 16 + j] = v.x; PYs[tid * 16 + j] = v.y; PZs[tid * 16 + j] = v.z;
    px[j] = v.x; py[j] = v.y; pz[j] = v.z; dm[j] = 1e10f;
  }
  __syncthreads();
  float cx = PXs[0], cy = PYs[0], cz = PZs[0];
  if (tid == 0) {
    new_xyzw[(size_t)b * 1024] = make_float4(cx, cy, cz, sq3(cx, cy, cz));
    out_xyz[b * 3072]        = cx;
    out_xyz[b * 3072 + 1024] = cy;
    out_xyz[b * 3072 + 2048] = cz;
  }
  for (int t = 1; t < 1024; ++t) {
    {
      float dx = px[0] - cx, dy = py[0] - cy, dz = pz[0] - cz;
      dm[0] = fminf(dm[0], sq3(dx, dy, dz));
    }
    float bv = dm[0];
    int bi = tid * 16;
#pragma unroll
    for (int j = 1; j < 16; ++j) {
      float dx = px[j] - cx, dy = py[j] - cy, dz = pz[j] - cz;
      float d = sq3(dx, dy, dz);
      dm[j] = fminf(dm[j], d);
      if (dm[j] > bv) { bv = dm[j]; bi = tid * 16 + j; }
    }
    u64 key = ((u64)__float_as_uint(bv) << 12) | (u32)(4095 - bi);
#pragma unroll
    for (int m = 1; m < 64; m <<= 1) {
      u64 o = __shfl_xor(key, m);
      key = (o > key) ? o : key;
    }
    if ((tid & 63) == 0) wk[tid >> 6] = key;
    __syncthreads();
    u64 ka = wk[0] > wk[1] ? wk[0] : wk[1];
    u64 kb = wk[2] > wk[3] ? wk[2] : wk[3];
    key = ka > kb ? ka : kb;
    const int win = 4095 - (int)(key & 0xfffu);
    cx = PXs[win]; cy = PYs[win]; cz = PZs[win];
    if (tid == 0) {
      new_xyzw[(size_t)b * 1024 + t] = make_float4(cx, cy, cz, sq3(cx, cy, cz));
      out_xyz[b * 3072 + t]        = cx;
      out_xyz[b * 3072 + 1024 + t] = cy;
      out_xyz[b * 3072 + 2048 + t] = cz;
    }
    __syncthreads();
  }
}

// ---------- KNN ----------
__global__ __launch_bounds__(128, 1) void k_knn(
    const float4* __restrict__ xyzw, const float4* __restrict__ qxyzw,
    int* __restrict__ knn) {
  __shared__ u64 LL[32 * 128];
  __shared__ int HH[16][8];
  const int tid = threadIdx.x;
  const int ql = tid >> 3, ss = tid & 7;
  const int b = blockIdx.x >> 6;
  const int q = ((blockIdx.x & 63) << 4) + ql;
  const float4 Q = qxyzw[(size_t)b * 1024 + q];
#pragma unroll
  for (int i = 0; i < 32; ++i) LL[i * 128 + tid] = ~0ULL;
  u64 worst = ~0ULL;
  const float4* P = xyzw + (size_t)b * 4096;
  for (int j = 0; j < 512; ++j) {
    const int n = j * 8 + ss;
    float4 p = P[n];
    float sqd = knn_sqd(Q, p);
    u32 u = __float_as_uint(sqd);
    u ^= (u32)((int)u >> 31) | 0x80000000u;
    u64 key = ((u64)u << 12) | (u32)n;
    if (key < worst) {
      int pos = 31;
      while (pos > 0 && LL[(pos - 1) * 128 + tid] > key) {
        LL[pos * 128 + tid] = LL[(pos - 1) * 128 + tid];
        --pos;
      }
      LL[pos * 128 + tid] = key;
      worst = LL[31 * 128 + tid];
    }
  }
  __syncthreads();
  if (ss == 0) {
#pragma unroll
    for (int t2 = 0; t2 < 8; ++t2) HH[ql][t2] = 0;
    const size_t ob = ((size_t)b * 1024 + q) * 32;
    for (int o = 0; o < 32; ++o) {
      u64 best = ~0ULL;
      int bs = 0;
#pragma unroll
      for (int t2 = 0; t2 < 8; ++t2) {
        int hh = HH[ql][t2];
        u64 v = (hh < 32) ? LL[hh * 128 + (ql * 8 + t2)] : ~0ULL;
        if (v < best) { best = v; bs = t2; }
      }
      HH[ql][bs]++;
      knn[ob + o] = (int)(best & 0xfffu);
    }
  }
}

// ---------- fused per-group transformer (MFMA GEMMs) ----------
DEV void ln_statsZ(float* __restrict__ X, float* __restrict__ MR, int tid) {
  const int r = tid >> 3, sub = tid & 7;
  float* row = X + r * 132 + sub * 16;
  float4 v[4];
  float s = 0.f;
#pragma unroll
  for (int j = 0; j < 4; ++j) {
    v[j] = *(const float4*)&row[j * 4];
    s += (v[j].x + v[j].y) + (v[j].z + v[j].w);
  }
  s += __shfl_xor(s, 1); s += __shfl_xor(s, 2); s += __shfl_xor(s, 4);
  const float m = s * 0.0078125f;
  float qv = 0.f;
#pragma unroll
  for (int j = 0; j < 4; ++j) {
    float a = v[j].x - m, b = v[j].y - m, c = v[j].z - m, d = v[j].w - m;
    qv += (a * a + b * b) + (c * c + d * d);
  }
  qv += __shfl_xor(qv, 1); qv += __shfl_xor(qv, 2); qv += __shfl_xor(qv, 4);
  const float sd = sqrtf(qv * 0.0078125f + 1e-5f);
  const float rstd = 1.0f / sd;
#pragma unroll
  for (int j = 0; j < 4; ++j) {
    row[j * 4 + 0] = (v[j].x - m) * rstd;
    row[j * 4 + 1] = (v[j].y - m) * rstd;
    row[j * 4 + 2] = (v[j].z - m) * rstd;
    row[j * 4 + 3] = (v[j].w - m) * rstd;
  }
  if (sub == 0) { MR[r * 4] = m; MR[r * 4 + 1] = rstd; MR[r * 4 + 2] = sd; }
}

DEV void split8(float4 x0, float4 x1, bf16x8& hi, bf16x8& lo) {
  float xs[8] = {x0.x, x0.y, x0.z, x0.w, x1.x, x1.y, x1.z, x1.w};
  union { u32 w[4]; bf16x8 v; } uh, ul;
#pragma unroll
  for (int i = 0; i < 4; ++i) {
    const u32 h0 = __float_as_uint(xs[2 * i]) >> 16;
    const u32 h1 = __float_as_uint(xs[2 * i + 1]) >> 16;
    const u32 l0 = f2bfu(xs[2 * i]     - __uint_as_float(h0 << 16));
    const u32 l1 = f2bfu(xs[2 * i + 1] - __uint_as_float(h1 << 16));
    uh.w[i] = h0 | (h1 << 16);
    ul.w[i] = l0 | (l1 << 16);
  }
  hi = uh.v; lo = ul.v;
}

// OUT[r][o] = sum_c IN[r][c]*W[o][c] + bias[o], W = Whi+Wlo (bf16 planes)
// MODE 0: store; 1: accumulate +=; 2: X-recon: OUT = OUT*sd + m + val
template <int K, int INS, int N, int OUTS, bool RELU, int MODE>
DEV void gemmM(const float* __restrict__ IN, const u16* __restrict__ whi,
               const u16* __restrict__ wlo, const float* __restrict__ bias,
               float* __restrict__ OUT, const float* __restrict__ MR, int tid) {
  constexpr int NT = N / 16;
  constexpr int CPW = NT / 2;  // col-tiles per wave
  const int wv = tid >> 6, wl = tid & 63;
  const int mt = wv >> 1;
  const int c0 = (wv & 1) * CPW;
  const int lm = wl & 15, kb = wl >> 4;
  const int arow = mt * 16 + lm;
  f32x4 acc[CPW];
#pragma unroll
  for (int t = 0; t < CPW; ++t) acc[t] = (f32x4){0.f, 0.f, 0.f, 0.f};
#pragma unroll
  for (int ks = 0; ks < K / 32; ++ks) {
    const int k0 = ks * 32 + kb * 8;
    const float* ap = &IN[arow * INS + k0];
    bf16x8 ahi, alo;
    split8(*(const float4*)ap, *(const float4*)(ap + 4), ahi, alo);
#pragma unroll
    for (int t = 0; t < CPW; ++t) {
      const int o = (c0 + t) * 16 + lm;
      const bf16x8 bhi = *(const bf16x8*)&whi[(size_t)o * K + k0];
      const bf16x8 blo = *(const bf16x8*)&wlo[(size_t)o * K + k0];
      acc[t] = MFMA(alo, bhi, acc[t]);
      acc[t] = MFMA(ahi, blo, acc[t]);
      acc[t] = MFMA(ahi, bhi, acc[t]);
    }
  }
#pragma unroll
  for (int t = 0; t < CPW; ++t) {
    const int col = (c0 + t) * 16 + lm;
    const float bv = bias[col];
#pragma unroll
    for (int j = 0; j < 4; ++j) {
      const int row = mt * 16 + kb * 4 + j;
      float val = acc[t][j] + bv;
      if (RELU) val = fmaxf(val, 0.f);
      if (MODE == 0) OUT[row * OUTS + col] = val;
      else if (MODE == 1) OUT[row * OUTS + col] += val;
      else {
        const float mm = MR[row * 4], sd = MR[row * 4 + 2];
        OUT[row * OUTS + col] = OUT[row * OUTS + col] * sd + mm + val;
      }
    }
  }
}

__global__ __launch_bounds__(256, 2) void k_xform(
    const float* __restrict__ feat, const float* __restrict__ featT, const int useT,
    const float4* __restrict__ xyzw, const int* __restrict__ knn,
    const float* __restrict__ wf, const float* __restrict__ wp,
    const u16* __restrict__ wb, float* __restrict__ out) {
  __shared__ __align__(16) float sm[18048];
  float* X  = sm;            // [32][132]
  float* Yf = sm + 4224;     // qkv rows stride 388; h at +8704 stride 68
  float* S  = sm + 16640;    // [32][36]
  float* MR = sm + 17792;    // [32][4]
  float4* GX = (float4*)(sm + 17920);
  const int g = blockIdx.x, b = g >> 10, tid = threadIdx.x;
  const int r = tid >> 3, sub = tid & 7, cs = sub * 16;
  const int n = knn[g * 32 + r];
  if (tid < 32) GX[tid] = xyzw[(size_t)b * 4096 + knn[g * 32 + tid]];
  if (useT) {
    const float* srcp = featT + ((size_t)(b * 4096 + n)) * 128 + cs;
    float* dst = &X[r * 132 + cs];
#pragma unroll
    for (int j = 0; j < 16; j += 4) *(float4*)&dst[j] = *(const float4*)&srcp[j];
  } else {
    const size_t fb0 = (size_t)b * 524288 + n;
    float* dst = &X[r * 132 + cs];
#pragma unroll
    for (int j = 0; j < 16; ++j) dst[j] = feat[fb0 + (size_t)(cs + j) * 4096];
  }
  __syncthreads();
  // h = relu(bn(gxyz @ w1.T + b1)) -> Yf[8704 + p*68 + c]
  {
    const float4 g4 = GX[r];
    const float rs = 1.0f / sqrtf(1.0f + 1e-5f);
#pragma unroll
    for (int jj = 0; jj < 8; ++jj) {
      const int c = sub + 8 * jj;
      float hv = g4.x * wf[W_PEW1 + c * 3] + g4.y * wf[W_PEW1 + c * 3 + 1] +
                 g4.z * wf[W_PEW1 + c * 3 + 2] + wf[W_PEB1 + c];
      hv = hv * (wf[W_BNG + c] * rs) + wf[W_BNB + c];
      Yf[8704 + r * 68 + c] = fmaxf(hv, 0.f);
    }
  }
  __syncthreads();
  // X += h @ w2.T + b2  (MFMA)
  gemmM<64, 68, 128, 132, false, 1>(Yf + 8704, wb + WB_P2HI, wb + WB_P2LO,
                                    wf + W_PEB2, X, MR, tid);
  __syncthreads();
  const float scale = 1.0f / sqrtf(32.0f);
#pragma unroll 1
  for (int l = 0; l < 2; ++l) {
    ln_statsZ(X, MR, tid);
    __syncthreads();
    gemmM<128, 132, 384, 388, false, 0>(X, wb + WB_QHI + l * 49152,
                                        wb + WB_QLO + l * 49152,
                                        wp + WP_QB + l * 384, Yf, MR, tid);
    __syncthreads();
#pragma unroll 1
    for (int h = 0; h < 4; ++h) {
      {  // scores
        const float* qi = &Yf[r * 388 + h * 32];
        float a[4] = {0.f, 0.f, 0.f, 0.f};
#pragma unroll
        for (int d = 0; d < 32; d += 4) {
          float4 q4 = *(const float4*)&qi[d];
#pragma unroll
          for (int jj = 0; jj < 4; ++jj) {
            float4 k4 = *(const float4*)&Yf[(sub + 8 * jj) * 388 + 128 + h * 32 + d];
            a[jj] += dot4(q4, k4);
          }
        }
#pragma unroll
        for (int jj = 0; jj < 4; ++jj) a[jj] *= scale;
        float mx = fmaxf(fmaxf(a[0], a[1]), fmaxf(a[2], a[3]));
        mx = fmaxf(mx, __shfl_xor(mx, 1));
        mx = fmaxf(mx, __shfl_xor(mx, 2));
        mx = fmaxf(mx, __shfl_xor(mx, 4));
        float e0 = __expf(a[0] - mx), e1 = __expf(a[1] - mx);
        float e2 = __expf(a[2] - mx), e3 = __expf(a[3] - mx);
        float s = (e0 + e1) + (e2 + e3);
        s += __shfl_xor(s, 1); s += __shfl_xor(s, 2); s += __shfl_xor(s, 4);
        const float inv = 1.0f / s;
        S[r * 36 + sub]      = e0 * inv;
        S[r * 36 + sub + 8]  = e1 * inv;
        S[r * 36 + sub + 16] = e2 * inv;
        S[r * 36 + sub + 24] = e3 * inv;
      }
      __syncthreads();
      {  // AV -> q-slice of head h
        const int d0 = sub * 4;
        float a0 = 0.f, a1 = 0.f, a2 = 0.f, a3 = 0.f;
        const float* pr = &S[r * 36];
#pragma unroll 8
        for (int j = 0; j < 32; ++j) {
          const float p = pr[j];
          float4 v4 = *(const float4*)&Yf[j * 388 + 256 + h * 32 + d0];
          a0 += p * v4.x; a1 += p * v4.y; a2 += p * v4.z; a3 += p * v4.w;
        }
        *(float4*)&Yf[r * 388 + h * 32 + d0] = make_float4(a0, a1, a2, a3);
      }
      __syncthreads();
    }
    gemmM<128, 388, 128, 132, false, 2>(Yf, wb + WB_OHI + l * 16384,
                                        wb + WB_OLO + l * 16384,
                                        wf + W_OUTB + l * 128, X, MR, tid);
    __syncthreads();
    ln_statsZ(X, MR, tid);
    __syncthreads();
    gemmM<128, 132, 256, 388, true, 0>(X, wb + WB_F1HI + l * 32768,
                                       wb + WB_F1LO + l * 32768,
                                       wp + WP_FB + l * 256, Yf, MR, tid);
    __syncthreads();
    gemmM<256, 388, 128, 132, false, 2>(Yf, wb + WB_F2HI + l * 32768,
                                        wb + WB_F2LO + l * 32768,
                                        wf + W_FF2B + l * 128, X, MR, tid);
    __syncthreads();
  }
  // pool -> S[0..127]
  if (tid < 128) {
    float m = X[tid];
#pragma unroll
    for (int rr = 1; rr < 32; ++rr) m = fmaxf(m, X[rr * 132 + tid]);
    S[tid] = m;
  }
  __syncthreads();
  // fc
  {
    float acc = wf[W_FCB + tid];
    const float* wr = wf + W_FCW + tid * 128;
#pragma unroll 8
    for (int c = 0; c < 128; c += 4) {
      float4 w4 = *(const float4*)&wr[c];
      float4 x4 = *(const float4*)&S[c];
      acc += dot4(x4, w4);
    }
    const int s = g & 1023;
    out[24576 + (size_t)b * 262144 + (size_t)tid * 1024 + s] = acc;
  }
}

extern "C" void kernel_launch(void* const* d_in, const int* in_sizes, int n_in,
                              void* d_out, int out_size, void* d_ws, size_t ws_size,
                              hipStream_t stream) {
  (void)in_sizes; (void)n_in; (void)out_size;
  char* ws = (char*)d_ws;
  float* wf    = (float*)ws;
  float4* xyzw = (float4*)(ws + OFF_XYZW);
  float4* newx = (float4*)(ws + OFF_NEWX);
  int* knni    = (int*)(ws + OFF_KNN);
  float* wp    = (float*)(ws + OFF_WP);
  u16* wb      = (u16*)(ws + OFF_WB);
  const float* xyz  = (const float*)d_in[0];
  const float* feat = (const float*)d_in[1];
  const int useT = (ws_size >= END_BIG) ? 1 : 0;
  float* featT = useT ? (float*)(ws + OFF_FEATT) : (float*)d_in[1];
  WArgs wa;
  for (int i = 0; i < 20; ++i) wa.p[i] = (const float*)d_in[2 + i];
  float* outp = (float*)d_out;

  hipLaunchKernelGGL(k_convw, dim3(1198), dim3(256), 0, stream, wa, wf);
  hipLaunchKernelGGL(k_prep, dim3(8), dim3(256), 0, stream, wf, wp, wb);
  hipLaunchKernelGGL(k_xyzw, dim3(128), dim3(256), 0, stream, xyz, xyzw);
  hipLaunchKernelGGL(k_pre, dim3(useT ? 4104 : 8), dim3(256), 0, stream,
                     xyzw, newx, outp, feat, featT);
  hipLaunchKernelGGL(k_knn, dim3(512), dim3(128), 0, stream, xyzw, newx, knni);
  hipLaunchKernelGGL(k_xform, dim3(8192), dim3(256), 0, stream,
                     feat, featT, useT, xyzw, knni, wf, wp, wb, outp);
}

// Round 6
// 3383.171 us; speedup vs baseline: 2.3808x; 1.1498x over previous
//
#include <hip/hip_runtime.h>

typedef unsigned int u32;
typedef unsigned long long u64;
typedef unsigned short u16;
typedef __attribute__((ext_vector_type(8))) short bf16x8;
typedef __attribute__((ext_vector_type(4))) float f32x4;

#define DEV __device__ __forceinline__

DEV float sq3(float x, float y, float z) {
#pragma clang fp contract(off)
  return (x * x + y * y) + z * z;
}
DEV float knn_sqd(float4 Q, float4 p) {
#pragma clang fp contract(off)
  float dot = (Q.x * p.x + Q.y * p.y) + Q.z * p.z;
  return (Q.w + p.w) - 2.0f * dot;
}
DEV float dot4(float4 a, float4 b) {
  return (a.x * b.x + a.y * b.y) + (a.z * b.z + a.w * b.w);
}
DEV u32 f2bfu(float f) {
  u32 u = __float_as_uint(f);
  return (u + 0x7fffu + ((u >> 16) & 1u)) >> 16;
}
DEV f32x4 MFMA(bf16x8 a, bf16x8 b, f32x4 c) {
  return __builtin_amdgcn_mfma_f32_16x16x32_bf16(a, b, c, 0, 0, 0);
}

// ---------- weight table (f32) ----------
enum : int {
  W_PEW1 = 0, W_PEB1 = 192, W_BNG = 256, W_BNB = 320,
  W_PEW2 = 384, W_PEB2 = 8576,
  W_INW  = 8704,   W_INB  = 107008,
  W_OUTW = 107776, W_OUTB = 140544,
  W_LN1G = 140800, W_LN1B = 141056, W_LN2G = 141312, W_LN2B = 141568,
  W_FF1W = 141824, W_FF1B = 207360,
  W_FF2W = 207872, W_FF2B = 273408,
  W_FCW  = 273664, W_FCB  = 306432,
  W_TOTAL = 306688
};
// folded f32 biases
enum : int { WP_QB = 0, WP_FB = 768, WP_TOTAL = 1280 };
// bf16 hi-only weight planes (u16 element offsets)
enum : int {
  WB_Q  = 0,       // [2][384][128]
  WB_O  = 98304,   // [2][128][128]
  WB_F1 = 131072,  // [2][256][128]
  WB_F2 = 196608,  // [2][128][256]
  WB_P2 = 262144,  // [128][64]
  WB_TOTAL = 270336
};

// ws byte offsets
static const size_t OFF_XYZW  = 1226752;  // [8*4096] float4
static const size_t OFF_NEWX  = 1751040;  // [8*1024] float4
static const size_t OFF_KNN   = 1882112;  // [8192*32] int
static const size_t OFF_WP    = 2930688;  // WP_TOTAL f32
static const size_t OFF_WB    = 2936064;  // WB_TOTAL u16 (540,672 B)
static const size_t OFF_FEATT = 3476736;  // OPTIONAL [8][4096][128] f32
static const size_t END_BIG   = 20253952;

struct WArgs { const float* p[20]; };

__global__ void k_convw(WArgs a, float* __restrict__ wf) {
  const int idx = blockIdx.x * 256 + threadIdx.x;
  if (idx >= W_TOTAL) return;
  const int sz[20] = {192, 64, 64, 64, 8192, 128, 98304, 768, 32768, 256,
                      256, 256, 256, 256, 65536, 512, 65536, 256, 32768, 256};
  int rem = idx;
#pragma unroll
  for (int s = 0; s < 20; ++s) {
    if (rem < sz[s]) { wf[idx] = a.p[s][rem]; return; }
    rem -= sz[s];
  }
}

// fold LN gamma/beta into qkv/ff1; emit bf16 hi-only planes for all GEMM weights
__global__ void k_prep(const float* __restrict__ wf, float* __restrict__ wp,
                       u16* __restrict__ wb) {
  const int idx = blockIdx.x * 256 + threadIdx.x;
  if (idx >= 1920) return;
  if (idx < 768) {  // qkv
    const int l = idx / 384, o = idx % 384;
    const float* W = wf + W_INW + l * 49152 + o * 128;
    const float* G = wf + W_LN1G + l * 128;
    const float* Bl = wf + W_LN1B + l * 128;
    float acc = wf[W_INB + l * 384 + o];
    u16* ph = wb + WB_Q + (l * 384 + o) * 128;
    for (int c = 0; c < 128; ++c) {
      const float w = W[c];
      acc += Bl[c] * w;
      ph[c] = (u16)f2bfu(w * G[c]);
    }
    wp[WP_QB + l * 384 + o] = acc;
  } else if (idx < 1280) {  // ff1
    const int j2 = idx - 768, l = j2 / 256, o = j2 % 256;
    const float* W = wf + W_FF1W + l * 32768 + o * 128;
    const float* G = wf + W_LN2G + l * 128;
    const float* Bl = wf + W_LN2B + l * 128;
    float acc = wf[W_FF1B + l * 256 + o];
    u16* ph = wb + WB_F1 + (l * 256 + o) * 128;
    for (int c = 0; c < 128; ++c) {
      const float w = W[c];
      acc += Bl[c] * w;
      ph[c] = (u16)f2bfu(w * G[c]);
    }
    wp[WP_FB + l * 256 + o] = acc;
  } else if (idx < 1536) {  // out-proj
    const int j2 = idx - 1280, l = j2 / 128, o = j2 % 128;
    const float* W = wf + W_OUTW + l * 16384 + o * 128;
    u16* ph = wb + WB_O + (l * 128 + o) * 128;
    for (int c = 0; c < 128; ++c) ph[c] = (u16)f2bfu(W[c]);
  } else if (idx < 1792) {  // ff2 (K=256)
    const int j2 = idx - 1536, l = j2 / 128, o = j2 % 128;
    const float* W = wf + W_FF2W + l * 32768 + o * 256;
    u16* ph = wb + WB_F2 + (l * 128 + o) * 256;
    for (int c = 0; c < 256; ++c) ph[c] = (u16)f2bfu(W[c]);
  } else {  // pe_w2 [128][64]
    const int o = idx - 1792;
    const float* W = wf + W_PEW2 + o * 64;
    u16* ph = wb + WB_P2 + o * 64;
    for (int c = 0; c < 64; ++c) ph[c] = (u16)f2bfu(W[c]);
  }
}

// xyz [B][3][N] f32 -> xyzw [B*N] float4 (x,y,z,sq)
__global__ void k_xyzw(const float* __restrict__ xyz, float4* __restrict__ xyzw) {
  const int i = blockIdx.x * 256 + threadIdx.x;
  const int b = i >> 12, n = i & 4095;
  const size_t s = (size_t)b * 12288 + n;
  float x = xyz[s], y = xyz[s + 4096], z = xyz[s + 8192];
  xyzw[i] = make_float4(x, y, z, sq3(x, y, z));
}

// ---------- fused: blocks 0..7 = FPS; blocks 8.. = feature transpose ----------
__global__ __launch_bounds__(256, 1) void k_pre(
    const float4* __restrict__ xyzw, float4* __restrict__ new_xyzw,
    float* __restrict__ out_xyz, const float* __restrict__ feat,
    float* __restrict__ featT) {
  __shared__ float PXs[4096], PYs[4096], PZs[4096];
  __shared__ u64 wk[4];
  __shared__ float tile[32][33];
  const int tid = threadIdx.x;
  if (blockIdx.x >= 8) {
    const int bb = blockIdx.x - 8;
    const int b = bb >> 9, r2 = bb & 511;
    const int n0 = (r2 >> 2) << 5, c0 = (r2 & 3) << 5;
    const int tx = tid & 31, ty = tid >> 5;
#pragma unroll
    for (int i = 0; i < 4; ++i) {
      const int c = c0 + ty + (i << 3);
      tile[ty + (i << 3)][tx] = feat[(size_t)b * 524288 + (size_t)c * 4096 + n0 + tx];
    }
    __syncthreads();
#pragma unroll
    for (int i = 0; i < 4; ++i) {
      const int n = n0 + ty + (i << 3);
      featT[(size_t)b * 524288 + (size_t)n * 128 + c0 + tx] = tile[tx][ty + (i << 3)];
    }
    return;
  }
  const int b = blockIdx.x;
  const float4* src = xyzw + (size_t)b * 4096;
  float px[16], py[16], pz[16], dm[16];
#pragma unroll
  for (int j = 0; j < 16; ++j) {
    float4 v = src[tid * 16 + j];
    PXs[tid * 16 + j] = v.x; PYs[tid * 16 + j] = v.y; PZs[tid * 16 + j] = v.z;
    px[j] = v.x; py[j] = v.y; pz[j] = v.z; dm[j] = 1e10f;
  }
  __syncthreads();
  float cx = PXs[0], cy = PYs[0], cz = PZs[0];
  if (tid == 0) {
    new_xyzw[(size_t)b * 1024] = make_float4(cx, cy, cz, sq3(cx, cy, cz));
    out_xyz[b * 3072]        = cx;
    out_xyz[b * 3072 + 1024] = cy;
    out_xyz[b * 3072 + 2048] = cz;
  }
  for (int t = 1; t < 1024; ++t) {
    {
      float dx = px[0] - cx, dy = py[0] - cy, dz = pz[0] - cz;
      dm[0] = fminf(dm[0], sq3(dx, dy, dz));
    }
    float bv = dm[0];
    int bi = tid * 16;
#pragma unroll
    for (int j = 1; j < 16; ++j) {
      float dx = px[j] - cx, dy = py[j] - cy, dz = pz[j] - cz;
      float d = sq3(dx, dy, dz);
      dm[j] = fminf(dm[j], d);
      if (dm[j] > bv) { bv = dm[j]; bi = tid * 16 + j; }
    }
    u64 key = ((u64)__float_as_uint(bv) << 12) | (u32)(4095 - bi);
#pragma unroll
    for (int m = 1; m < 64; m <<= 1) {
      u64 o = __shfl_xor(key, m);
      key = (o > key) ? o : key;
    }
    if ((tid & 63) == 0) wk[tid >> 6] = key;
    __syncthreads();
    u64 ka = wk[0] > wk[1] ? wk[0] : wk[1];
    u64 kb2 = wk[2] > wk[3] ? wk[2] : wk[3];
    key = ka > kb2 ? ka : kb2;
    const int win = 4095 - (int)(key & 0xfffu);
    cx = PXs[win]; cy = PYs[win]; cz = PZs[win];
    if (tid == 0) {
      new_xyzw[(size_t)b * 1024 + t] = make_float4(cx, cy, cz, sq3(cx, cy, cz));
      out_xyz[b * 3072 + t]        = cx;
      out_xyz[b * 3072 + 1024 + t] = cy;
      out_xyz[b * 3072 + 2048 + t] = cz;
    }
    __syncthreads();
  }
}

// ---------- KNN ----------
__global__ __launch_bounds__(128, 1) void k_knn(
    const float4* __restrict__ xyzw, const float4* __restrict__ qxyzw,
    int* __restrict__ knn) {
  __shared__ u64 LL[32 * 128];
  __shared__ int HH[16][8];
  const int tid = threadIdx.x;
  const int ql = tid >> 3, ss = tid & 7;
  const int b = blockIdx.x >> 6;
  const int q = ((blockIdx.x & 63) << 4) + ql;
  const float4 Q = qxyzw[(size_t)b * 1024 + q];
#pragma unroll
  for (int i = 0; i < 32; ++i) LL[i * 128 + tid] = ~0ULL;
  u64 worst = ~0ULL;
  const float4* P = xyzw + (size_t)b * 4096;
  for (int j = 0; j < 512; ++j) {
    const int n = j * 8 + ss;
    float4 p = P[n];
    float sqd = knn_sqd(Q, p);
    u32 u = __float_as_uint(sqd);
    u ^= (u32)((int)u >> 31) | 0x80000000u;
    u64 key = ((u64)u << 12) | (u32)n;
    if (key < worst) {
      int pos = 31;
      while (pos > 0 && LL[(pos - 1) * 128 + tid] > key) {
        LL[pos * 128 + tid] = LL[(pos - 1) * 128 + tid];
        --pos;
      }
      LL[pos * 128 + tid] = key;
      worst = LL[31 * 128 + tid];
    }
  }
  __syncthreads();
  if (ss == 0) {
#pragma unroll
    for (int t2 = 0; t2 < 8; ++t2) HH[ql][t2] = 0;
    const size_t ob = ((size_t)b * 1024 + q) * 32;
    for (int o = 0; o < 32; ++o) {
      u64 best = ~0ULL;
      int bs = 0;
#pragma unroll
      for (int t2 = 0; t2 < 8; ++t2) {
        int hh = HH[ql][t2];
        u64 v = (hh < 32) ? LL[hh * 128 + (ql * 8 + t2)] : ~0ULL;
        if (v < best) { best = v; bs = t2; }
      }
      HH[ql][bs]++;
      knn[ob + o] = (int)(best & 0xfffu);
    }
  }
}

// ---------- fused per-group transformer v3 (MFMA everywhere) ----------
// LDS (floats): X[32*132]@0, ZH u16[4096]@4224, QK u16[8192]@6272,
// Vt u16[4096]@10368, GX float4[32]@12416 -> 12544 f = 50,176 B -> 3 blocks/CU.

// LN: read f32 X, write z as bf16 to ZH (swizzled). X preserved.
DEV void ln_z(const float* __restrict__ X, u16* __restrict__ ZH, int tid) {
  const int r = tid >> 3, sub = tid & 7;
  const float* row = X + r * 132 + sub * 16;
  float4 v[4];
  float s = 0.f;
#pragma unroll
  for (int j = 0; j < 4; ++j) {
    v[j] = *(const float4*)&row[j * 4];
    s += (v[j].x + v[j].y) + (v[j].z + v[j].w);
  }
  s += __shfl_xor(s, 1); s += __shfl_xor(s, 2); s += __shfl_xor(s, 4);
  const float m = s * 0.0078125f;
  float qv = 0.f;
#pragma unroll
  for (int j = 0; j < 4; ++j) {
    float a = v[j].x - m, b = v[j].y - m, c = v[j].z - m, d = v[j].w - m;
    qv += (a * a + b * b) + (c * c + d * d);
  }
  qv += __shfl_xor(qv, 1); qv += __shfl_xor(qv, 2); qv += __shfl_xor(qv, 4);
  const float rstd = 1.0f / sqrtf(qv * 0.0078125f + 1e-5f);
  const int mask = (r & 7) << 3;
  float z[16];
#pragma unroll
  for (int j = 0; j < 4; ++j) {
    z[j * 4]     = (v[j].x - m) * rstd;
    z[j * 4 + 1] = (v[j].y - m) * rstd;
    z[j * 4 + 2] = (v[j].z - m) * rstd;
    z[j * 4 + 3] = (v[j].w - m) * rstd;
  }
#pragma unroll
  for (int i = 0; i < 8; ++i) {
    const u32 w = f2bfu(z[2 * i]) | (f2bfu(z[2 * i + 1]) << 16);
    *(u32*)&ZH[r * 128 + ((sub * 16 + 2 * i) ^ mask)] = w;
  }
}

// OUT = A(bf16 LDS, swizzled) @ W(bf16 global)^T + bias
// MODE 0: qkv -> QK bf16 (cols<256) + Vt bf16 (cols>=256)
// MODE 1: f32 accumulate into X ;  MODE 2: relu -> QK bf16
template <int K, int AINS, int N, int MODE>
DEV void gemmM(const u16* __restrict__ A, const u16* __restrict__ wb,
               const float* __restrict__ bias, float* __restrict__ X,
               u16* __restrict__ QKp, u16* __restrict__ Vtp, int tid) {
  constexpr int CPW = N / 32;
  const int wv = tid >> 6, wl = tid & 63;
  const int mt = wv >> 1, c0 = (wv & 1) * CPW;
  const int lm = wl & 15, kb = wl >> 4;
  const int ar = mt * 16 + lm;
  const int amask = (ar & 7) << 3;
  f32x4 acc[CPW];
#pragma unroll
  for (int t = 0; t < CPW; ++t) acc[t] = (f32x4){0.f, 0.f, 0.f, 0.f};
#pragma unroll
  for (int ks = 0; ks < K / 32; ++ks) {
    const int k0 = ks * 32 + kb * 8;
    const bf16x8 a = *(const bf16x8*)&A[ar * AINS + (k0 ^ amask)];
#pragma unroll
    for (int t = 0; t < CPW; ++t) {
      const int o = (c0 + t) * 16 + lm;
      const bf16x8 b = *(const bf16x8*)&wb[(size_t)o * K + k0];
      acc[t] = MFMA(a, b, acc[t]);
    }
  }
#pragma unroll
  for (int t = 0; t < CPW; ++t) {
    const int col = (c0 + t) * 16 + lm;
    const float bv = bias[col];
    if (MODE == 0 && col >= 256) {  // V -> transposed Vt[d][j]
      const int d = col - 256;
      const int j0 = mt * 16 + kb * 4;
      const int base = d * 32 + (j0 ^ ((d & 3) << 3));
      *(u32*)&Vtp[base]     = f2bfu(acc[t][0] + bv) | (f2bfu(acc[t][1] + bv) << 16);
      *(u32*)&Vtp[base + 2] = f2bfu(acc[t][2] + bv) | (f2bfu(acc[t][3] + bv) << 16);
    } else {
#pragma unroll
      for (int j = 0; j < 4; ++j) {
        const int row = mt * 16 + kb * 4 + j;
        float val = acc[t][j] + bv;
        if (MODE == 2) val = fmaxf(val, 0.f);
        if (MODE == 1) X[row * 132 + col] += val;
        else QKp[row * 256 + (col ^ ((row & 7) << 3))] = (u16)f2bfu(val);
      }
    }
  }
}

__global__ __launch_bounds__(256, 3) void k_xform(
    const float* __restrict__ feat, const float* __restrict__ featT, const int useT,
    const float4* __restrict__ xyzw, const int* __restrict__ knn,
    const float* __restrict__ wf, const float* __restrict__ wp,
    const u16* __restrict__ wb, float* __restrict__ out) {
  __shared__ __align__(16) float sm[12544];
  float* X   = sm;                       // [32][132] f32 residual
  u16* ZH    = (u16*)(sm + 4224);        // [32][128] bf16: z / h / P(4x1024)
  u16* QKp   = (u16*)(sm + 6272);        // [32][256] bf16: Q,K / attn-out / ff1-out
  u16* Vtp   = (u16*)(sm + 10368);       // [128][32] bf16: V transposed
  float4* GX = (float4*)(sm + 12416);    // [32]
  const int g = blockIdx.x, b = g >> 10, tid = threadIdx.x;
  const int r = tid >> 3, sub = tid & 7, cs = sub * 16;
  const int n = knn[g * 32 + r];
  if (tid < 32) GX[tid] = xyzw[(size_t)b * 4096 + knn[g * 32 + tid]];
  if (useT) {
    const float* srcp = featT + ((size_t)(b * 4096 + n)) * 128 + cs;
    float* dst = &X[r * 132 + cs];
#pragma unroll
    for (int j = 0; j < 16; j += 4) *(float4*)&dst[j] = *(const float4*)&srcp[j];
  } else {
    const size_t fb0 = (size_t)b * 524288 + n;
    float* dst = &X[r * 132 + cs];
#pragma unroll
    for (int j = 0; j < 16; ++j) dst[j] = feat[fb0 + (size_t)(cs + j) * 4096];
  }
  __syncthreads();
  // h = relu(bn(gxyz @ w1.T + b1)) -> ZH bf16 (cols 0..63, swizzled)
  {
    const float4 g4 = GX[r];
    const float rs = 1.0f / sqrtf(1.0f + 1e-5f);
    const int mask = (r & 7) << 3;
#pragma unroll
    for (int i = 0; i < 4; ++i) {
      u32 wpk = 0;
#pragma unroll
      for (int e = 0; e < 2; ++e) {
        const int c = sub * 8 + 2 * i + e;
        float hv = g4.x * wf[W_PEW1 + c * 3] + g4.y * wf[W_PEW1 + c * 3 + 1] +
                   g4.z * wf[W_PEW1 + c * 3 + 2] + wf[W_PEB1 + c];
        hv = hv * (wf[W_BNG + c] * rs) + wf[W_BNB + c];
        hv = fmaxf(hv, 0.f);
        wpk |= f2bfu(hv) << (16 * e);
      }
      *(u32*)&ZH[r * 128 + ((sub * 8 + 2 * i) ^ mask)] = wpk;
    }
  }
  __syncthreads();
  // X += h @ w2.T + b2
  gemmM<64, 128, 128, 1>(ZH, wb + WB_P2, wf + W_PEB2, X, QKp, Vtp, tid);
  __syncthreads();
#pragma unroll 1
  for (int l = 0; l < 2; ++l) {
    ln_z(X, ZH, tid);
    __syncthreads();
    gemmM<128, 128, 384, 0>(ZH, wb + WB_Q + l * 49152, wp + WP_QB + l * 384,
                            X, QKp, Vtp, tid);
    __syncthreads();
    // ---- attention: one head per wave, all-MFMA ----
    {
      const int wv = tid >> 6, wl = tid & 63;
      const int hh = wv, lm = wl & 15, kb = wl >> 4;
      bf16x8 qf[2], kf[2];
#pragma unroll
      for (int t = 0; t < 2; ++t) {
        const int rr = t * 16 + lm;
        const int msk = (rr & 7) << 3;
        qf[t] = *(const bf16x8*)&QKp[rr * 256 + ((hh * 32 + kb * 8) ^ msk)];
        kf[t] = *(const bf16x8*)&QKp[rr * 256 + ((128 + hh * 32 + kb * 8) ^ msk)];
      }
      const f32x4 zz = {0.f, 0.f, 0.f, 0.f};
      f32x4 sc[2][2];
      sc[0][0] = MFMA(qf[0], kf[0], zz); sc[0][1] = MFMA(qf[0], kf[1], zz);
      sc[1][0] = MFMA(qf[1], kf[0], zz); sc[1][1] = MFMA(qf[1], kf[1], zz);
      const float scale = 0.1767766952966369f;  // 1/sqrt(32)
      u16* Pp = ZH + hh * 1024;
#pragma unroll
      for (int mtl = 0; mtl < 2; ++mtl) {
#pragma unroll
        for (int j = 0; j < 4; ++j) {
          float a0 = sc[mtl][0][j] * scale, a1 = sc[mtl][1][j] * scale;
          float mx = fmaxf(a0, a1);
          mx = fmaxf(mx, __shfl_xor(mx, 1));
          mx = fmaxf(mx, __shfl_xor(mx, 2));
          mx = fmaxf(mx, __shfl_xor(mx, 4));
          mx = fmaxf(mx, __shfl_xor(mx, 8));
          const float e0 = __expf(a0 - mx), e1 = __expf(a1 - mx);
          float sum = e0 + e1;
          sum += __shfl_xor(sum, 1); sum += __shfl_xor(sum, 2);
          sum += __shfl_xor(sum, 4); sum += __shfl_xor(sum, 8);
          const float inv = 1.0f / sum;
          const int q = mtl * 16 + kb * 4 + j;
          const int qm = (q & 3) << 3;
          Pp[q * 32 + (lm ^ qm)]        = (u16)f2bfu(e0 * inv);
          Pp[q * 32 + ((16 + lm) ^ qm)] = (u16)f2bfu(e1 * inv);
        }
      }
      __syncthreads();  // P visible (also orders same-wave LDS)
      bf16x8 pf[2], vf[2];
#pragma unroll
      for (int t = 0; t < 2; ++t) {
        const int q = t * 16 + lm;
        pf[t] = *(const bf16x8*)&Pp[q * 32 + ((kb * 8) ^ ((q & 3) << 3))];
        const int d = hh * 32 + t * 16 + lm;
        vf[t] = *(const bf16x8*)&Vtp[d * 32 + ((kb * 8) ^ ((d & 3) << 3))];
      }
      f32x4 av[2][2];
      av[0][0] = MFMA(pf[0], vf[0], zz); av[0][1] = MFMA(pf[0], vf[1], zz);
      av[1][0] = MFMA(pf[1], vf[0], zz); av[1][1] = MFMA(pf[1], vf[1], zz);
#pragma unroll
      for (int mtl = 0; mtl < 2; ++mtl)
#pragma unroll
        for (int ntl = 0; ntl < 2; ++ntl)
#pragma unroll
          for (int j = 0; j < 4; ++j) {
            const int row = mtl * 16 + kb * 4 + j;
            const int col = hh * 32 + ntl * 16 + lm;
            QKp[row * 256 + (col ^ ((row & 7) << 3))] = (u16)f2bfu(av[mtl][ntl][j]);
          }
    }
    __syncthreads();
    // X += attn_out @ W_out^T + b
    gemmM<128, 256, 128, 1>(QKp, wb + WB_O + l * 16384, wf + W_OUTB + l * 128,
                            X, QKp, Vtp, tid);
    __syncthreads();
    ln_z(X, ZH, tid);
    __syncthreads();
    gemmM<128, 128, 256, 2>(ZH, wb + WB_F1 + l * 32768, wp + WP_FB + l * 256,
                            X, QKp, Vtp, tid);
    __syncthreads();
    gemmM<256, 256, 128, 1>(QKp, wb + WB_F2 + l * 32768, wf + W_FF2B + l * 128,
                            X, QKp, Vtp, tid);
    __syncthreads();
  }
  // pool -> ZH (as f32)
  float* pooled = (float*)ZH;
  if (tid < 128) {
    float m = X[tid];
#pragma unroll
    for (int rr = 1; rr < 32; ++rr) m = fmaxf(m, X[rr * 132 + tid]);
    pooled[tid] = m;
  }
  __syncthreads();
  // fc
  {
    float acc = wf[W_FCB + tid];
    const float* wr = wf + W_FCW + tid * 128;
#pragma unroll 8
    for (int c = 0; c < 128; c += 4) {
      float4 w4 = *(const float4*)&wr[c];
      float4 x4 = *(const float4*)&pooled[c];
      acc += dot4(x4, w4);
    }
    const int s = g & 1023;
    out[24576 + (size_t)b * 262144 + (size_t)tid * 1024 + s] = acc;
  }
}

extern "C" void kernel_launch(void* const* d_in, const int* in_sizes, int n_in,
                              void* d_out, int out_size, void* d_ws, size_t ws_size,
                              hipStream_t stream) {
  (void)in_sizes; (void)n_in; (void)out_size;
  char* ws = (char*)d_ws;
  float* wf    = (float*)ws;
  float4* xyzw = (float4*)(ws + OFF_XYZW);
  float4* newx = (float4*)(ws + OFF_NEWX);
  int* knni    = (int*)(ws + OFF_KNN);
  float* wp    = (float*)(ws + OFF_WP);
  u16* wb      = (u16*)(ws + OFF_WB);
  const float* xyz  = (const float*)d_in[0];
  const float* feat = (const float*)d_in[1];
  const int useT = (ws_size >= END_BIG) ? 1 : 0;
  float* featT = useT ? (float*)(ws + OFF_FEATT) : (float*)d_in[1];
  WArgs wa;
  for (int i = 0; i < 20; ++i) wa.p[i] = (const float*)d_in[2 + i];
  float* outp = (float*)d_out;

  hipLaunchKernelGGL(k_convw, dim3(1198), dim3(256), 0, stream, wa, wf);
  hipLaunchKernelGGL(k_prep, dim3(8), dim3(256), 0, stream, wf, wp, wb);
  hipLaunchKernelGGL(k_xyzw, dim3(128), dim3(256), 0, stream, xyz, xyzw);
  hipLaunchKernelGGL(k_pre, dim3(useT ? 4104 : 8), dim3(256), 0, stream,
                     xyzw, newx, outp, feat, featT);
  hipLaunchKernelGGL(k_knn, dim3(512), dim3(128), 0, stream, xyzw, newx, knni);
  hipLaunchKernelGGL(k_xform, dim3(8192), dim3(256), 0, stream,
                     feat, featT, useT, xyzw, knni, wf, wp, wb, outp);
}

// Round 9
// 2731.157 us; speedup vs baseline: 2.9492x; 1.2387x over previous
//
#include <hip/hip_runtime.h>

typedef unsigned int u32;
typedef unsigned long long u64;
typedef unsigned short u16;
typedef __attribute__((ext_vector_type(8))) short bf16x8;
typedef __attribute__((ext_vector_type(4))) float f32x4;

#define DEV __device__ __forceinline__

DEV float sq3(float x, float y, float z) {
#pragma clang fp contract(off)
  return (x * x + y * y) + z * z;
}
DEV float knn_sqd(float4 Q, float4 p) {
#pragma clang fp contract(off)
  float dot = (Q.x * p.x + Q.y * p.y) + Q.z * p.z;
  return (Q.w + p.w) - 2.0f * dot;
}
DEV float dot4(float4 a, float4 b) {
  return (a.x * b.x + a.y * b.y) + (a.z * b.z + a.w * b.w);
}
DEV u32 f2bfu(float f) {
  u32 u = __float_as_uint(f);
  return (u + 0x7fffu + ((u >> 16) & 1u)) >> 16;
}
DEV f32x4 MFMA(bf16x8 a, bf16x8 b, f32x4 c) {
  return __builtin_amdgcn_mfma_f32_16x16x32_bf16(a, b, c, 0, 0, 0);
}

// ---------- weight table (f32) ----------
enum : int {
  W_PEW1 = 0, W_PEB1 = 192, W_BNG = 256, W_BNB = 320,
  W_PEW2 = 384, W_PEB2 = 8576,
  W_INW  = 8704,   W_INB  = 107008,
  W_OUTW = 107776, W_OUTB = 140544,
  W_LN1G = 140800, W_LN1B = 141056, W_LN2G = 141312, W_LN2B = 141568,
  W_FF1W = 141824, W_FF1B = 207360,
  W_FF2W = 207872, W_FF2B = 273408,
  W_FCW  = 273664, W_FCB  = 306432,
  W_TOTAL = 306688
};
// folded f32 biases
enum : int { WP_QB = 0, WP_FB = 768, WP_TOTAL = 1280 };
// bf16 hi-only weight planes (u16 element offsets)
enum : int {
  WB_Q  = 0,       // [2][384][128]
  WB_O  = 98304,   // [2][128][128]
  WB_F1 = 131072,  // [2][256][128]
  WB_F2 = 196608,  // [2][128][256]
  WB_P2 = 262144,  // [128][64]
  WB_TOTAL = 270336
};

// ws byte offsets
static const size_t OFF_XYZW  = 1226752;  // [8*4096] float4
static const size_t OFF_NEWX  = 1751040;  // [8*1024] float4
static const size_t OFF_KNN   = 1882112;  // [8192*32] int
static const size_t OFF_WP    = 2930688;  // WP_TOTAL f32
static const size_t OFF_WB    = 2936064;  // WB_TOTAL u16 (540,672 B)
static const size_t OFF_FEATT = 3476736;  // OPTIONAL [8][4096][128] f32
static const size_t END_BIG   = 20253952;

struct WArgs { const float* p[20]; };

__global__ void k_convw(WArgs a, float* __restrict__ wf) {
  const int idx = blockIdx.x * 256 + threadIdx.x;
  if (idx >= W_TOTAL) return;
  const int sz[20] = {192, 64, 64, 64, 8192, 128, 98304, 768, 32768, 256,
                      256, 256, 256, 256, 65536, 512, 65536, 256, 32768, 256};
  int rem = idx;
#pragma unroll
  for (int s = 0; s < 20; ++s) {
    if (rem < sz[s]) { wf[idx] = a.p[s][rem]; return; }
    rem -= sz[s];
  }
}

// fold LN gamma/beta into qkv/ff1; emit bf16 hi-only planes for all GEMM weights
__global__ void k_prep(const float* __restrict__ wf, float* __restrict__ wp,
                       u16* __restrict__ wb) {
  const int idx = blockIdx.x * 256 + threadIdx.x;
  if (idx >= 1920) return;
  if (idx < 768) {  // qkv
    const int l = idx / 384, o = idx % 384;
    const float* W = wf + W_INW + l * 49152 + o * 128;
    const float* G = wf + W_LN1G + l * 128;
    const float* Bl = wf + W_LN1B + l * 128;
    float acc = wf[W_INB + l * 384 + o];
    u16* ph = wb + WB_Q + (l * 384 + o) * 128;
    for (int c = 0; c < 128; ++c) {
      const float w = W[c];
      acc += Bl[c] * w;
      ph[c] = (u16)f2bfu(w * G[c]);
    }
    wp[WP_QB + l * 384 + o] = acc;
  } else if (idx < 1280) {  // ff1
    const int j2 = idx - 768, l = j2 / 256, o = j2 % 256;
    const float* W = wf + W_FF1W + l * 32768 + o * 128;
    const float* G = wf + W_LN2G + l * 128;
    const float* Bl = wf + W_LN2B + l * 128;
    float acc = wf[W_FF1B + l * 256 + o];
    u16* ph = wb + WB_F1 + (l * 256 + o) * 128;
    for (int c = 0; c < 128; ++c) {
      const float w = W[c];
      acc += Bl[c] * w;
      ph[c] = (u16)f2bfu(w * G[c]);
    }
    wp[WP_FB + l * 256 + o] = acc;
  } else if (idx < 1536) {  // out-proj
    const int j2 = idx - 1280, l = j2 / 128, o = j2 % 128;
    const float* W = wf + W_OUTW + l * 16384 + o * 128;
    u16* ph = wb + WB_O + (l * 128 + o) * 128;
    for (int c = 0; c < 128; ++c) ph[c] = (u16)f2bfu(W[c]);
  } else if (idx < 1792) {  // ff2 (K=256)
    const int j2 = idx - 1536, l = j2 / 128, o = j2 % 128;
    const float* W = wf + W_FF2W + l * 32768 + o * 256;
    u16* ph = wb + WB_F2 + (l * 128 + o) * 256;
    for (int c = 0; c < 256; ++c) ph[c] = (u16)f2bfu(W[c]);
  } else {  // pe_w2 [128][64]
    const int o = idx - 1792;
    const float* W = wf + W_PEW2 + o * 64;
    u16* ph = wb + WB_P2 + o * 64;
    for (int c = 0; c < 64; ++c) ph[c] = (u16)f2bfu(W[c]);
  }
}

// xyz [B][3][N] f32 -> xyzw [B*N] float4 (x,y,z,sq)
__global__ void k_xyzw(const float* __restrict__ xyz, float4* __restrict__ xyzw) {
  const int i = blockIdx.x * 256 + threadIdx.x;
  const int b = i >> 12, n = i & 4095;
  const size_t s = (size_t)b * 12288 + n;
  float x = xyz[s], y = xyz[s + 4096], z = xyz[s + 8192];
  xyzw[i] = make_float4(x, y, z, sq3(x, y, z));
}

// ---------- fused: blocks 0..7 = FPS; blocks 8.. = feature transpose ----------
__global__ __launch_bounds__(256, 1) void k_pre(
    const float4* __restrict__ xyzw, float4* __restrict__ new_xyzw,
    float* __restrict__ out_xyz, const float* __restrict__ feat,
    float* __restrict__ featT) {
  __shared__ float PXs[4096], PYs[4096], PZs[4096];
  __shared__ u64 wk[4];
  __shared__ float tile[32][33];
  const int tid = threadIdx.x;
  if (blockIdx.x >= 8) {
    const int bb = blockIdx.x - 8;
    const int b = bb >> 9, r2 = bb & 511;
    const int n0 = (r2 >> 2) << 5, c0 = (r2 & 3) << 5;
    const int tx = tid & 31, ty = tid >> 5;
#pragma unroll
    for (int i = 0; i < 4; ++i) {
      const int c = c0 + ty + (i << 3);
      tile[ty + (i << 3)][tx] =
          __builtin_nontemporal_load(&feat[(size_t)b * 524288 + (size_t)c * 4096 + n0 + tx]);
    }
    __syncthreads();
#pragma unroll
    for (int i = 0; i < 4; ++i) {
      const int n = n0 + ty + (i << 3);
      __builtin_nontemporal_store(tile[tx][ty + (i << 3)],
          &featT[(size_t)b * 524288 + (size_t)n * 128 + c0 + tx]);
    }
    return;
  }
  const int b = blockIdx.x;
  const float4* src = xyzw + (size_t)b * 4096;
  float px[16], py[16], pz[16], dm[16];
#pragma unroll
  for (int j = 0; j < 16; ++j) {
    float4 v = src[tid * 16 + j];
    PXs[tid * 16 + j] = v.x; PYs[tid * 16 + j] = v.y; PZs[tid * 16 + j] = v.z;
    px[j] = v.x; py[j] = v.y; pz[j] = v.z; dm[j] = 1e10f;
  }
  __syncthreads();
  float cx = PXs[0], cy = PYs[0], cz = PZs[0];
  if (tid == 0) {
    new_xyzw[(size_t)b * 1024] = make_float4(cx, cy, cz, sq3(cx, cy, cz));
    out_xyz[b * 3072]        = cx;
    out_xyz[b * 3072 + 1024] = cy;
    out_xyz[b * 3072 + 2048] = cz;
  }
  for (int t = 1; t < 1024; ++t) {
    {
      float dx = px[0] - cx, dy = py[0] - cy, dz = pz[0] - cz;
      dm[0] = fminf(dm[0], sq3(dx, dy, dz));
    }
    float bv = dm[0];
    int bi = tid * 16;
#pragma unroll
    for (int j = 1; j < 16; ++j) {
      float dx = px[j] - cx, dy = py[j] - cy, dz = pz[j] - cz;
      float d = sq3(dx, dy, dz);
      dm[j] = fminf(dm[j], d);
      if (dm[j] > bv) { bv = dm[j]; bi = tid * 16 + j; }
    }
    u64 key = ((u64)__float_as_uint(bv) << 12) | (u32)(4095 - bi);
#pragma unroll
    for (int m = 1; m < 64; m <<= 1) {
      u64 o = __shfl_xor(key, m);
      key = (o > key) ? o : key;
    }
    if ((tid & 63) == 0) wk[tid >> 6] = key;
    __syncthreads();
    u64 ka = wk[0] > wk[1] ? wk[0] : wk[1];
    u64 kb2 = wk[2] > wk[3] ? wk[2] : wk[3];
    key = ka > kb2 ? ka : kb2;
    const int win = 4095 - (int)(key & 0xfffu);
    cx = PXs[win]; cy = PYs[win]; cz = PZs[win];
    if (tid == 0) {
      new_xyzw[(size_t)b * 1024 + t] = make_float4(cx, cy, cz, sq3(cx, cy, cz));
      out_xyz[b * 3072 + t]        = cx;
      out_xyz[b * 3072 + 1024 + t] = cy;
      out_xyz[b * 3072 + 2048 + t] = cz;
    }
    __syncthreads();
  }
}

// ---------- KNN ----------
__global__ __launch_bounds__(128, 1) void k_knn(
    const float4* __restrict__ xyzw, const float4* __restrict__ qxyzw,
    int* __restrict__ knn) {
  __shared__ u64 LL[32 * 128];
  __shared__ int HH[16][8];
  const int tid = threadIdx.x;
  const int ql = tid >> 3, ss = tid & 7;
  const int b = blockIdx.x >> 6;
  const int q = ((blockIdx.x & 63) << 4) + ql;
  const float4 Q = qxyzw[(size_t)b * 1024 + q];
#pragma unroll
  for (int i = 0; i < 32; ++i) LL[i * 128 + tid] = ~0ULL;
  u64 worst = ~0ULL;
  const float4* P = xyzw + (size_t)b * 4096;
  for (int j = 0; j < 512; ++j) {
    const int n = j * 8 + ss;
    float4 p = P[n];
    float sqd = knn_sqd(Q, p);
    u32 u = __float_as_uint(sqd);
    u ^= (u32)((int)u >> 31) | 0x80000000u;
    u64 key = ((u64)u << 12) | (u32)n;
    if (key < worst) {
      int pos = 31;
      while (pos > 0 && LL[(pos - 1) * 128 + tid] > key) {
        LL[pos * 128 + tid] = LL[(pos - 1) * 128 + tid];
        --pos;
      }
      LL[pos * 128 + tid] = key;
      worst = LL[31 * 128 + tid];
    }
  }
  __syncthreads();
  if (ss == 0) {
#pragma unroll
    for (int t2 = 0; t2 < 8; ++t2) HH[ql][t2] = 0;
    const size_t ob = ((size_t)b * 1024 + q) * 32;
    for (int o = 0; o < 32; ++o) {
      u64 best = ~0ULL;
      int bs = 0;
#pragma unroll
      for (int t2 = 0; t2 < 8; ++t2) {
        int hh = HH[ql][t2];
        u64 v = (hh < 32) ? LL[hh * 128 + (ql * 8 + t2)] : ~0ULL;
        if (v < best) { best = v; bs = t2; }
      }
      HH[ql][bs]++;
      knn[ob + o] = (int)(best & 0xfffu);
    }
  }
}

// ---------- fused per-group transformer v4 ----------
// LDS (floats): X[32*132]@0, ZH u16[4096]@4224, QK u16[8192]@6272,
// Vt u16[4096]@10368, GX float4[32]@12416 -> 12544 f = 50,176 B -> 3 blocks/CU.

DEV void ln_z(const float* __restrict__ X, u16* __restrict__ ZH, int tid) {
  const int r = tid >> 3, sub = tid & 7;
  const float* row = X + r * 132 + sub * 16;
  float4 v[4];
  float s = 0.f;
#pragma unroll
  for (int j = 0; j < 4; ++j) {
    v[j] = *(const float4*)&row[j * 4];
    s += (v[j].x + v[j].y) + (v[j].z + v[j].w);
  }
  s += __shfl_xor(s, 1); s += __shfl_xor(s, 2); s += __shfl_xor(s, 4);
  const float m = s * 0.0078125f;
  float qv = 0.f;
#pragma unroll
  for (int j = 0; j < 4; ++j) {
    float a = v[j].x - m, b = v[j].y - m, c = v[j].z - m, d = v[j].w - m;
    qv += (a * a + b * b) + (c * c + d * d);
  }
  qv += __shfl_xor(qv, 1); qv += __shfl_xor(qv, 2); qv += __shfl_xor(qv, 4);
  const float rstd = 1.0f / sqrtf(qv * 0.0078125f + 1e-5f);
  const int mask = (r & 7) << 3;
  float z[16];
#pragma unroll
  for (int j = 0; j < 4; ++j) {
    z[j * 4]     = (v[j].x - m) * rstd;
    z[j * 4 + 1] = (v[j].y - m) * rstd;
    z[j * 4 + 2] = (v[j].z - m) * rstd;
    z[j * 4 + 3] = (v[j].w - m) * rstd;
  }
#pragma unroll
  for (int i = 0; i < 8; ++i) {
    const u32 w = f2bfu(z[2 * i]) | (f2bfu(z[2 * i + 1]) << 16);
    *(u32*)&ZH[r * 128 + ((sub * 16 + 2 * i) ^ mask)] = w;
  }
}

// N=128 GEMM: OUT[r][o] = sum_c A[r][c]*W[o][c] + bias[o], bf16 MFMA.
// All B fragments of a <=4-kstep chunk prefetched before the MFMA burst.
// MODE 0: store bf16 -> OUTp cols co..co+127 (swizzled)
// MODE 1: f32 accumulate into X
// MODE 2: relu, store bf16 -> OUTp (like 0)
// MODE 3: write transposed Vt
template <int K, int AINS, int MODE>
DEV void gemm128(const u16* __restrict__ A, const u16* __restrict__ wbp,
                 const float* __restrict__ bias, float* __restrict__ X,
                 u16* __restrict__ OUTp, int co, u16* __restrict__ Vtp, int tid) {
  const int wv = tid >> 6, wl = tid & 63;
  const int mt = wv >> 1, c0 = (wv & 1) * 64;
  const int lm = wl & 15, kb = wl >> 4;
  const int ar = mt * 16 + lm;
  const int amask = (ar & 7) << 3;
  constexpr int KS = K / 32;
  constexpr int CH = (KS > 4) ? 4 : KS;
  f32x4 acc[4];
#pragma unroll
  for (int t = 0; t < 4; ++t) acc[t] = (f32x4){0.f, 0.f, 0.f, 0.f};
#pragma unroll
  for (int kc = 0; kc < KS / CH; ++kc) {
    bf16x8 bfr[CH][4];
#pragma unroll
    for (int ks = 0; ks < CH; ++ks) {
      const int k0 = (kc * CH + ks) * 32 + kb * 8;
#pragma unroll
      for (int t = 0; t < 4; ++t) {
        const int o = c0 + t * 16 + lm;
        bfr[ks][t] = *(const bf16x8*)&wbp[(size_t)o * K + k0];
      }
    }
#pragma unroll
    for (int ks = 0; ks < CH; ++ks) {
      const int k0 = (kc * CH + ks) * 32 + kb * 8;
      const bf16x8 a = *(const bf16x8*)&A[ar * AINS + (k0 ^ amask)];
#pragma unroll
      for (int t = 0; t < 4; ++t) acc[t] = MFMA(a, bfr[ks][t], acc[t]);
    }
  }
#pragma unroll
  for (int t = 0; t < 4; ++t) {
    const int col = c0 + t * 16 + lm;
    const float bv = bias[col];
    if (MODE == 3) {
      const int j0 = mt * 16 + kb * 4;
      const int base = col * 32 + (j0 ^ ((col & 3) << 3));
      *(u32*)&Vtp[base]     = f2bfu(acc[t][0] + bv) | (f2bfu(acc[t][1] + bv) << 16);
      *(u32*)&Vtp[base + 2] = f2bfu(acc[t][2] + bv) | (f2bfu(acc[t][3] + bv) << 16);
    } else {
#pragma unroll
      for (int j = 0; j < 4; ++j) {
        const int row = mt * 16 + kb * 4 + j;
        float val = acc[t][j] + bv;
        if (MODE == 2) val = fmaxf(val, 0.f);
        if (MODE == 1) X[row * 132 + col] += val;
        else OUTp[row * 256 + ((co + col) ^ ((row & 7) << 3))] = (u16)f2bfu(val);
      }
    }
  }
}

__global__ __launch_bounds__(256, 2) void k_xform(
    const float* __restrict__ feat, const float* __restrict__ featT, const int useT,
    const float4* __restrict__ xyzw, const int* __restrict__ knn,
    const float* __restrict__ wf, const float* __restrict__ wp,
    const u16* __restrict__ wb, float* __restrict__ out) {
  __shared__ __align__(16) float sm[12544];
  float* X   = sm;                       // [32][132] f32 residual
  u16* ZH    = (u16*)(sm + 4224);        // [32][128] bf16: z / h / P(4x1024)
  u16* QKp   = (u16*)(sm + 6272);        // [32][256] bf16: Q,K / attn-out / ff1-out
  u16* Vtp   = (u16*)(sm + 10368);       // [128][32] bf16: V transposed
  float4* GX = (float4*)(sm + 12416);    // [32]
  const int g = blockIdx.x, b = g >> 10, tid = threadIdx.x;
  const int r = tid >> 3, sub = tid & 7, cs = sub * 16;
  const int n = knn[g * 32 + r];
  if (tid < 32) GX[tid] = xyzw[(size_t)b * 4096 + knn[g * 32 + tid]];
  if (useT) {
    const f32x4* srcp = (const f32x4*)(featT + ((size_t)(b * 4096 + n)) * 128 + cs);
    float* dst = &X[r * 132 + cs];
#pragma unroll
    for (int j = 0; j < 4; ++j)
      *(f32x4*)&dst[j * 4] = __builtin_nontemporal_load(&srcp[j]);
  } else {
    const size_t fb0 = (size_t)b * 524288 + n;
    float* dst = &X[r * 132 + cs];
#pragma unroll
    for (int j = 0; j < 16; ++j)
      dst[j] = __builtin_nontemporal_load(&feat[fb0 + (size_t)(cs + j) * 4096]);
  }
  __syncthreads();
  // h = relu(bn(gxyz @ w1.T + b1)) -> ZH bf16 (cols 0..63, swizzled)
  {
    const float4 g4 = GX[r];
    const float rs = 1.0f / sqrtf(1.0f + 1e-5f);
    const int mask = (r & 7) << 3;
#pragma unroll
    for (int i = 0; i < 4; ++i) {
      u32 wpk = 0;
#pragma unroll
      for (int e = 0; e < 2; ++e) {
        const int c = sub * 8 + 2 * i + e;
        float hv = g4.x * wf[W_PEW1 + c * 3] + g4.y * wf[W_PEW1 + c * 3 + 1] +
                   g4.z * wf[W_PEW1 + c * 3 + 2] + wf[W_PEB1 + c];
        hv = hv * (wf[W_BNG + c] * rs) + wf[W_BNB + c];
        hv = fmaxf(hv, 0.f);
        wpk |= f2bfu(hv) << (16 * e);
      }
      *(u32*)&ZH[r * 128 + ((sub * 8 + 2 * i) ^ mask)] = wpk;
    }
  }
  __syncthreads();
  // X += h @ w2.T + b2
  gemm128<64, 128, 1>(ZH, wb + WB_P2, wf + W_PEB2, X, QKp, 0, Vtp, tid);
  __syncthreads();
#pragma unroll 1
  for (int l = 0; l < 2; ++l) {
    ln_z(X, ZH, tid);
    __syncthreads();
    // Q, K -> QKp cols 0..255 ; V -> Vt (no inter-call deps)
    gemm128<128, 128, 0>(ZH, wb + WB_Q + l * 49152,            wp + WP_QB + l * 384,       X, QKp, 0,   Vtp, tid);
    gemm128<128, 128, 0>(ZH, wb + WB_Q + l * 49152 + 16384,    wp + WP_QB + l * 384 + 128, X, QKp, 128, Vtp, tid);
    gemm128<128, 128, 3>(ZH, wb + WB_Q + l * 49152 + 32768,    wp + WP_QB + l * 384 + 256, X, QKp, 0,   Vtp, tid);
    __syncthreads();
    // ---- attention: one head per wave, all-MFMA ----
    {
      const int wv = tid >> 6, wl = tid & 63;
      const int hh = wv, lm = wl & 15, kb = wl >> 4;
      bf16x8 qf[2], kf[2];
#pragma unroll
      for (int t = 0; t < 2; ++t) {
        const int rr = t * 16 + lm;
        const int msk = (rr & 7) << 3;
        qf[t] = *(const bf16x8*)&QKp[rr * 256 + ((hh * 32 + kb * 8) ^ msk)];
        kf[t] = *(const bf16x8*)&QKp[rr * 256 + ((128 + hh * 32 + kb * 8) ^ msk)];
      }
      const f32x4 zz = {0.f, 0.f, 0.f, 0.f};
      f32x4 sc[2][2];
      sc[0][0] = MFMA(qf[0], kf[0], zz); sc[0][1] = MFMA(qf[0], kf[1], zz);
      sc[1][0] = MFMA(qf[1], kf[0], zz); sc[1][1] = MFMA(qf[1], kf[1], zz);
      const float scale = 0.1767766952966369f;  // 1/sqrt(32)
      u16* Pp = ZH + hh * 1024;
#pragma unroll
      for (int mtl = 0; mtl < 2; ++mtl) {
#pragma unroll
        for (int j = 0; j < 4; ++j) {
          float a0 = sc[mtl][0][j] * scale, a1 = sc[mtl][1][j] * scale;
          float mx = fmaxf(a0, a1);
          mx = fmaxf(mx, __shfl_xor(mx, 1));
          mx = fmaxf(mx, __shfl_xor(mx, 2));
          mx = fmaxf(mx, __shfl_xor(mx, 4));
          mx = fmaxf(mx, __shfl_xor(mx, 8));
          const float e0 = __expf(a0 - mx), e1 = __expf(a1 - mx);
          float sum = e0 + e1;
          sum += __shfl_xor(sum, 1); sum += __shfl_xor(sum, 2);
          sum += __shfl_xor(sum, 4); sum += __shfl_xor(sum, 8);
          const float inv = 1.0f / sum;
          const int q = mtl * 16 + kb * 4 + j;
          const int qm = (q & 3) << 3;
          Pp[q * 32 + (lm ^ qm)]        = (u16)f2bfu(e0 * inv);
          Pp[q * 32 + ((16 + lm) ^ qm)] = (u16)f2bfu(e1 * inv);
        }
      }
      __syncthreads();  // P visible
      bf16x8 pf[2], vf[2];
#pragma unroll
      for (int t = 0; t < 2; ++t) {
        const int q = t * 16 + lm;
        pf[t] = *(const bf16x8*)&Pp[q * 32 + ((kb * 8) ^ ((q & 3) << 3))];
        const int d = hh * 32 + t * 16 + lm;
        vf[t] = *(const bf16x8*)&Vtp[d * 32 + ((kb * 8) ^ ((d & 3) << 3))];
      }
      f32x4 av[2][2];
      av[0][0] = MFMA(pf[0], vf[0], zz); av[0][1] = MFMA(pf[0], vf[1], zz);
      av[1][0] = MFMA(pf[1], vf[0], zz); av[1][1] = MFMA(pf[1], vf[1], zz);
#pragma unroll
      for (int mtl = 0; mtl < 2; ++mtl)
#pragma unroll
        for (int ntl = 0; ntl < 2; ++ntl)
#pragma unroll
          for (int j = 0; j < 4; ++j) {
            const int row = mtl * 16 + kb * 4 + j;
            const int col = hh * 32 + ntl * 16 + lm;
            QKp[row * 256 + (col ^ ((row & 7) << 3))] = (u16)f2bfu(av[mtl][ntl][j]);
          }
    }
    __syncthreads();
    // X += attn_out @ W_out^T + b
    gemm128<128, 256, 1>(QKp, wb + WB_O + l * 16384, wf + W_OUTB + l * 128,
                         X, QKp, 0, Vtp, tid);
    __syncthreads();
    ln_z(X, ZH, tid);
    __syncthreads();
    gemm128<128, 128, 2>(ZH, wb + WB_F1 + l * 32768,         wp + WP_FB + l * 256,       X, QKp, 0,   Vtp, tid);
    gemm128<128, 128, 2>(ZH, wb + WB_F1 + l * 32768 + 16384, wp + WP_FB + l * 256 + 128, X, QKp, 128, Vtp, tid);
    __syncthreads();
    gemm128<256, 256, 1>(QKp, wb + WB_F2 + l * 32768, wf + W_FF2B + l * 128,
                         X, QKp, 0, Vtp, tid);
    __syncthreads();
  }
  // pool -> ZH (as f32)
  float* pooled = (float*)ZH;
  if (tid < 128) {
    float m = X[tid];
#pragma unroll
    for (int rr = 1; rr < 32; ++rr) m = fmaxf(m, X[rr * 132 + tid]);
    pooled[tid] = m;
  }
  __syncthreads();
  // fc
  {
    float acc = wf[W_FCB + tid];
    const float* wr = wf + W_FCW + tid * 128;
#pragma unroll 8
    for (int c = 0; c < 128; c += 4) {
      float4 w4 = *(const float4*)&wr[c];
      float4 x4 = *(const float4*)&pooled[c];
      acc += dot4(x4, w4);
    }
    const int s = g & 1023;
    __builtin_nontemporal_store(acc,
        &out[24576 + (size_t)b * 262144 + (size_t)tid * 1024 + s]);
  }
}

extern "C" void kernel_launch(void* const* d_in, const int* in_sizes, int n_in,
                              void* d_out, int out_size, void* d_ws, size_t ws_size,
                              hipStream_t stream) {
  (void)in_sizes; (void)n_in; (void)out_size;
  char* ws = (char*)d_ws;
  float* wf    = (float*)ws;
  float4* xyzw = (float4*)(ws + OFF_XYZW);
  float4* newx = (float4*)(ws + OFF_NEWX);
  int* knni    = (int*)(ws + OFF_KNN);
  float* wp    = (float*)(ws + OFF_WP);
  u16* wb      = (u16*)(ws + OFF_WB);
  const float* xyz  = (const float*)d_in[0];
  const float* feat = (const float*)d_in[1];
  const int useT = (ws_size >= END_BIG) ? 1 : 0;
  float* featT = useT ? (float*)(ws + OFF_FEATT) : (float*)d_in[1];
  WArgs wa;
  for (int i = 0; i < 20; ++i) wa.p[i] = (const float*)d_in[2 + i];
  float* outp = (float*)d_out;

  hipLaunchKernelGGL(k_convw, dim3(1198), dim3(256), 0, stream, wa, wf);
  hipLaunchKernelGGL(k_prep, dim3(8), dim3(256), 0, stream, wf, wp, wb);
  hipLaunchKernelGGL(k_xyzw, dim3(128), dim3(256), 0, stream, xyz, xyzw);
  hipLaunchKernelGGL(k_pre, dim3(useT ? 4104 : 8), dim3(256), 0, stream,
                     xyzw, newx, outp, feat, featT);
  hipLaunchKernelGGL(k_knn, dim3(512), dim3(128), 0, stream, xyzw, newx, knni);
  hipLaunchKernelGGL(k_xform, dim3(8192), dim3(256), 0, stream,
                     feat, featT, useT, xyzw, knni, wf, wp, wb, outp);
}

// Round 10
// 2571.138 us; speedup vs baseline: 3.1327x; 1.0622x over previous
//
#include <hip/hip_runtime.h>

typedef unsigned int u32;
typedef unsigned long long u64;
typedef unsigned short u16;
typedef __attribute__((ext_vector_type(8))) short bf16x8;
typedef __attribute__((ext_vector_type(4))) float f32x4;

#define DEV __device__ __forceinline__

DEV float sq3(float x, float y, float z) {
#pragma clang fp contract(off)
  return (x * x + y * y) + z * z;
}
DEV float knn_sqd(float4 Q, float4 p) {
#pragma clang fp contract(off)
  float dot = (Q.x * p.x + Q.y * p.y) + Q.z * p.z;
  return (Q.w + p.w) - 2.0f * dot;
}
DEV float dot4(float4 a, float4 b) {
  return (a.x * b.x + a.y * b.y) + (a.z * b.z + a.w * b.w);
}
DEV u32 f2bfu(float f) {
  u32 u = __float_as_uint(f);
  return (u + 0x7fffu + ((u >> 16) & 1u)) >> 16;
}
DEV f32x4 MFMA(bf16x8 a, bf16x8 b, f32x4 c) {
  return __builtin_amdgcn_mfma_f32_16x16x32_bf16(a, b, c, 0, 0, 0);
}

// ---------- weight table (f32) ----------
enum : int {
  W_PEW1 = 0, W_PEB1 = 192, W_BNG = 256, W_BNB = 320,
  W_PEW2 = 384, W_PEB2 = 8576,
  W_INW  = 8704,   W_INB  = 107008,
  W_OUTW = 107776, W_OUTB = 140544,
  W_LN1G = 140800, W_LN1B = 141056, W_LN2G = 141312, W_LN2B = 141568,
  W_FF1W = 141824, W_FF1B = 207360,
  W_FF2W = 207872, W_FF2B = 273408,
  W_FCW  = 273664, W_FCB  = 306432,
  W_TOTAL = 306688
};
enum : int { WP_QB = 0, WP_FB = 768, WP_TOTAL = 1280 };
enum : int {
  WB_Q  = 0,       // [2][384][128]
  WB_O  = 98304,   // [2][128][128]
  WB_F1 = 131072,  // [2][256][128]
  WB_F2 = 196608,  // [2][128][256]
  WB_P2 = 262144,  // [128][64]
  WB_TOTAL = 270336
};

// ws byte offsets
static const size_t OFF_XYZW  = 1226752;
static const size_t OFF_NEWX  = 1751040;
static const size_t OFF_KNN   = 1882112;
static const size_t OFF_WP    = 2930688;
static const size_t OFF_WB    = 2936064;
static const size_t OFF_FEATT = 3476736;  // OPTIONAL [8][4096][128] f32
static const size_t END_BIG   = 20253952;

struct WArgs { const float* p[20]; };

// ---------- fused setup: blocks 0..1197 convw, 1198..1205 prep, 1206..1333 xyzw ----------
__global__ void k_setup(WArgs a, float* __restrict__ wf, float* __restrict__ wp,
                        u16* __restrict__ wb, const float* __restrict__ xyz,
                        float4* __restrict__ xyzw) {
  const int blk = blockIdx.x, tid = threadIdx.x;
  if (blk < 1198) {
    const int idx = blk * 256 + tid;
    if (idx >= W_TOTAL) return;
    const int sz[20] = {192, 64, 64, 64, 8192, 128, 98304, 768, 32768, 256,
                        256, 256, 256, 256, 65536, 512, 65536, 256, 32768, 256};
    int rem = idx;
#pragma unroll
    for (int s = 0; s < 20; ++s) {
      if (rem < sz[s]) { wf[idx] = a.p[s][rem]; return; }
      rem -= sz[s];
    }
    return;
  }
  if (blk < 1206) {
    const int idx = (blk - 1198) * 256 + tid;
    if (idx >= 1920) return;
    if (idx < 768) {  // qkv: fold ln1
      const int l = idx / 384, o = idx % 384;
      const float* W = a.p[6] + l * 49152 + o * 128;
      const float* G = a.p[10] + l * 128;
      const float* Bl = a.p[11] + l * 128;
      float acc = a.p[7][l * 384 + o];
      u16* ph = wb + WB_Q + (l * 384 + o) * 128;
      for (int c = 0; c < 128; ++c) {
        const float w = W[c];
        acc += Bl[c] * w;
        ph[c] = (u16)f2bfu(w * G[c]);
      }
      wp[WP_QB + l * 384 + o] = acc;
    } else if (idx < 1280) {  // ff1: fold ln2
      const int j2 = idx - 768, l = j2 / 256, o = j2 % 256;
      const float* W = a.p[14] + l * 32768 + o * 128;
      const float* G = a.p[12] + l * 128;
      const float* Bl = a.p[13] + l * 128;
      float acc = a.p[15][l * 256 + o];
      u16* ph = wb + WB_F1 + (l * 256 + o) * 128;
      for (int c = 0; c < 128; ++c) {
        const float w = W[c];
        acc += Bl[c] * w;
        ph[c] = (u16)f2bfu(w * G[c]);
      }
      wp[WP_FB + l * 256 + o] = acc;
    } else if (idx < 1536) {  // out-proj
      const int j2 = idx - 1280, l = j2 / 128, o = j2 % 128;
      const float* W = a.p[8] + l * 16384 + o * 128;
      u16* ph = wb + WB_O + (l * 128 + o) * 128;
      for (int c = 0; c < 128; ++c) ph[c] = (u16)f2bfu(W[c]);
    } else if (idx < 1792) {  // ff2
      const int j2 = idx - 1536, l = j2 / 128, o = j2 % 128;
      const float* W = a.p[16] + l * 32768 + o * 256;
      u16* ph = wb + WB_F2 + (l * 128 + o) * 256;
      for (int c = 0; c < 256; ++c) ph[c] = (u16)f2bfu(W[c]);
    } else {  // pe_w2
      const int o = idx - 1792;
      const float* W = a.p[4] + o * 64;
      u16* ph = wb + WB_P2 + o * 64;
      for (int c = 0; c < 64; ++c) ph[c] = (u16)f2bfu(W[c]);
    }
    return;
  }
  {
    const int i = (blk - 1206) * 256 + tid;
    const int b = i >> 12, n = i & 4095;
    const size_t s = (size_t)b * 12288 + n;
    float x = xyz[s], y = xyz[s + 4096], z = xyz[s + 8192];
    xyzw[i] = make_float4(x, y, z, sq3(x, y, z));
  }
}

// ---------- fused: blocks 0..7 = FPS; blocks 8.. = feature transpose ----------
__global__ __launch_bounds__(256, 1) void k_pre(
    const float4* __restrict__ xyzw, float4* __restrict__ new_xyzw,
    float* __restrict__ out_xyz, const float* __restrict__ feat,
    float* __restrict__ featT) {
  __shared__ float PXs[4096], PYs[4096], PZs[4096];
  __shared__ u64 wkk[2][4];
  __shared__ float tile[32][33];
  const int tid = threadIdx.x;
  if (blockIdx.x >= 8) {
    const int bb = blockIdx.x - 8;
    const int b = bb >> 9, r2 = bb & 511;
    const int n0 = (r2 >> 2) << 5, c0 = (r2 & 3) << 5;
    const int tx = tid & 31, ty = tid >> 5;
#pragma unroll
    for (int i = 0; i < 4; ++i) {
      const int c = c0 + ty + (i << 3);
      tile[ty + (i << 3)][tx] =
          __builtin_nontemporal_load(&feat[(size_t)b * 524288 + (size_t)c * 4096 + n0 + tx]);
    }
    __syncthreads();
#pragma unroll
    for (int i = 0; i < 4; ++i) {
      const int n = n0 + ty + (i << 3);
      __builtin_nontemporal_store(tile[tx][ty + (i << 3)],
          &featT[(size_t)b * 524288 + (size_t)n * 128 + c0 + tx]);
    }
    return;
  }
  // FPS — exact replica of reference scan
  const int b = blockIdx.x;
  const float4* src = xyzw + (size_t)b * 4096;
  float px[16], py[16], pz[16], dm[16];
#pragma unroll
  for (int j = 0; j < 16; ++j) {
    float4 v = src[tid * 16 + j];
    PXs[tid * 16 + j] = v.x; PYs[tid * 16 + j] = v.y; PZs[tid * 16 + j] = v.z;
    px[j] = v.x; py[j] = v.y; pz[j] = v.z; dm[j] = 1e10f;
  }
  __syncthreads();
  float cx = PXs[0], cy = PYs[0], cz = PZs[0];
  if (tid == 0) {
    new_xyzw[(size_t)b * 1024] = make_float4(cx, cy, cz, sq3(cx, cy, cz));
    out_xyz[b * 3072]        = cx;
    out_xyz[b * 3072 + 1024] = cy;
    out_xyz[b * 3072 + 2048] = cz;
  }
  for (int t = 1; t < 1024; ++t) {
    {
      float dx = px[0] - cx, dy = py[0] - cy, dz = pz[0] - cz;
      dm[0] = fminf(dm[0], sq3(dx, dy, dz));
    }
    float bv = dm[0];
    int bi = tid * 16;
#pragma unroll
    for (int j = 1; j < 16; ++j) {
      float dx = px[j] - cx, dy = py[j] - cy, dz = pz[j] - cz;
      float d = sq3(dx, dy, dz);
      dm[j] = fminf(dm[j], d);
      if (dm[j] > bv) { bv = dm[j]; bi = tid * 16 + j; }  // strict > keeps lowest idx
    }
    // exact wave argmax: f32 max, then lowest lane (lane ranges are idx-ordered)
    float mx = bv;
    mx = fmaxf(mx, __shfl_xor(mx, 1));
    mx = fmaxf(mx, __shfl_xor(mx, 2));
    mx = fmaxf(mx, __shfl_xor(mx, 4));
    mx = fmaxf(mx, __shfl_xor(mx, 8));
    mx = fmaxf(mx, __shfl_xor(mx, 16));
    mx = fmaxf(mx, __shfl_xor(mx, 32));
    const u64 ball = __ballot(bv == mx);
    const int wl2 = (int)(__ffsll((unsigned long long)ball) - 1);
    const int wbi = __shfl(bi, wl2);
    if ((tid & 63) == 0)
      wkk[t & 1][tid >> 6] = ((u64)__float_as_uint(mx) << 12) | (u32)(4095 - wbi);
    __syncthreads();
    const u64* wk = wkk[t & 1];
    u64 ka = wk[0] > wk[1] ? wk[0] : wk[1];
    u64 kb2 = wk[2] > wk[3] ? wk[2] : wk[3];
    u64 key = ka > kb2 ? ka : kb2;
    const int win = 4095 - (int)(key & 0xfffu);
    cx = PXs[win]; cy = PYs[win]; cz = PZs[win];
    if (tid == 0) {
      new_xyzw[(size_t)b * 1024 + t] = make_float4(cx, cy, cz, sq3(cx, cy, cz));
      out_xyz[b * 3072 + t]        = cx;
      out_xyz[b * 3072 + 1024 + t] = cy;
      out_xyz[b * 3072 + 2048 + t] = cz;
    }
  }
}

// ---------- KNN: register-resident top-32, branch-free shift network ----------
// 4 queries/block, 32 threads/query (128 candidates each), 2048 blocks
__global__ __launch_bounds__(128, 1) void k_knn(
    const float4* __restrict__ xyzw, const float4* __restrict__ qxyzw,
    int* __restrict__ knn) {
  __shared__ u64 LL[32 * 128];
  __shared__ int HH[4][32];
  const int tid = threadIdx.x;
  const int ql = tid >> 5, ss = tid & 31;
  const int b = blockIdx.x >> 8;
  const int q = ((blockIdx.x & 255) << 2) + ql;
  const float4 Q = qxyzw[(size_t)b * 1024 + q];
  u64 L[32];
#pragma unroll
  for (int i = 0; i < 32; ++i) L[i] = ~0ULL;
  const float4* P = xyzw + (size_t)b * 4096;
#pragma unroll 2
  for (int j = 0; j < 128; ++j) {
    const int n = j * 32 + ss;
    float4 p = P[n];
    float sqd = knn_sqd(Q, p);
    u32 u = __float_as_uint(sqd);
    u ^= (u32)((int)u >> 31) | 0x80000000u;  // total-order transform
    const u64 key = ((u64)u << 12) | (u32)n;
    if (key < L[31]) {
#pragma unroll
      for (int i = 31; i >= 1; --i) {
        const u64 lo = L[i] < key ? L[i] : key;      // min(L[i], key)
        L[i] = lo > L[i - 1] ? lo : L[i - 1];        // max(lo, L[i-1])
      }
      L[0] = L[0] < key ? L[0] : key;
    }
  }
#pragma unroll
  for (int i = 0; i < 32; ++i) LL[i * 128 + tid] = L[i];
  __syncthreads();
  if (ss == 0) {
#pragma unroll
    for (int t2 = 0; t2 < 32; ++t2) HH[ql][t2] = 0;
    const size_t ob = ((size_t)b * 1024 + q) * 32;
    for (int o = 0; o < 32; ++o) {
      u64 best = ~0ULL;
      int bs = 0;
#pragma unroll
      for (int t2 = 0; t2 < 32; ++t2) {
        const int hh = HH[ql][t2];
        const u64 v = (hh < 32) ? LL[hh * 128 + (ql * 32 + t2)] : ~0ULL;
        if (v < best) { best = v; bs = t2; }
      }
      HH[ql][bs]++;
      knn[ob + o] = (int)(best & 0xfffu);
    }
  }
}

// ---------- fused per-group transformer v5 (small-code) ----------
// LDS (floats): X[32*132]@0, ZH u16[4096]@4224, QK u16[8192]@6272,
// Vt u16[4096]@10368, GX float4[32]@12416 -> 50,176 B -> 3 blocks/CU.

__device__ __attribute__((noinline)) void ln_z(
    const float* __restrict__ X, u16* __restrict__ ZH, int tid) {
  const int r = tid >> 3, sub = tid & 7;
  const float* row = X + r * 132 + sub * 16;
  float4 v[4];
  float s = 0.f;
#pragma unroll
  for (int j = 0; j < 4; ++j) {
    v[j] = *(const float4*)&row[j * 4];
    s += (v[j].x + v[j].y) + (v[j].z + v[j].w);
  }
  s += __shfl_xor(s, 1); s += __shfl_xor(s, 2); s += __shfl_xor(s, 4);
  const float m = s * 0.0078125f;
  float qv = 0.f;
#pragma unroll
  for (int j = 0; j < 4; ++j) {
    float a = v[j].x - m, b = v[j].y - m, c = v[j].z - m, d = v[j].w - m;
    qv += (a * a + b * b) + (c * c + d * d);
  }
  qv += __shfl_xor(qv, 1); qv += __shfl_xor(qv, 2); qv += __shfl_xor(qv, 4);
  const float rstd = 1.0f / sqrtf(qv * 0.0078125f + 1e-5f);
  const int mask = (r & 7) << 3;
  float z[16];
#pragma unroll
  for (int j = 0; j < 4; ++j) {
    z[j * 4]     = (v[j].x - m) * rstd;
    z[j * 4 + 1] = (v[j].y - m) * rstd;
    z[j * 4 + 2] = (v[j].z - m) * rstd;
    z[j * 4 + 3] = (v[j].w - m) * rstd;
  }
#pragma unroll
  for (int i = 0; i < 8; ++i) {
    const u32 w = f2bfu(z[2 * i]) | (f2bfu(z[2 * i + 1]) << 16);
    *(u32*)&ZH[r * 128 + ((sub * 16 + 2 * i) ^ mask)] = w;
  }
}

// single runtime GEMM body: OUT[r][o] = sum_c A[r][c]*W[o][c] + bias[o]
// mode 0: store bf16->OUTp ; 1: f32 accum into X ; 2: relu+store ; 3: write Vt
__device__ __attribute__((noinline)) void gemmR(
    const u16* __restrict__ A, int AINS, const u16* __restrict__ wbp, int K,
    const float* __restrict__ bias, float* __restrict__ X,
    u16* __restrict__ OUTp, int co, u16* __restrict__ Vtp, int mode, int tid) {
  const int wv = tid >> 6, wl = tid & 63;
  const int mt = wv >> 1, c0 = (wv & 1) * 64;
  const int lm = wl & 15, kb = wl >> 4;
  const int ar = mt * 16 + lm;
  const int amask = (ar & 7) << 3;
  const int KS = K >> 5;
  f32x4 acc[4];
#pragma unroll
  for (int t = 0; t < 4; ++t) acc[t] = (f32x4){0.f, 0.f, 0.f, 0.f};
  const u16* wp0 = wbp + (size_t)(c0 + lm) * K + kb * 8;
  const size_t rstride = (size_t)16 * K;
  bf16x8 cur[4], nxt[4];
#pragma unroll
  for (int t = 0; t < 4; ++t) cur[t] = *(const bf16x8*)(wp0 + t * rstride);
  for (int ks = 0; ks < KS; ++ks) {
    if (ks + 1 < KS) {
      const u16* wn = wp0 + (ks + 1) * 32;
#pragma unroll
      for (int t = 0; t < 4; ++t) nxt[t] = *(const bf16x8*)(wn + t * rstride);
    }
    const bf16x8 a = *(const bf16x8*)&A[ar * AINS + ((ks * 32 + kb * 8) ^ amask)];
#pragma unroll
    for (int t = 0; t < 4; ++t) acc[t] = MFMA(a, cur[t], acc[t]);
#pragma unroll
    for (int t = 0; t < 4; ++t) cur[t] = nxt[t];
  }
#pragma unroll
  for (int t = 0; t < 4; ++t) {
    const int col = c0 + t * 16 + lm;
    const float bv = bias[col];
    if (mode == 3) {
      const int j0 = mt * 16 + kb * 4;
      const int base = col * 32 + (j0 ^ ((col & 3) << 3));
      *(u32*)&Vtp[base]     = f2bfu(acc[t][0] + bv) | (f2bfu(acc[t][1] + bv) << 16);
      *(u32*)&Vtp[base + 2] = f2bfu(acc[t][2] + bv) | (f2bfu(acc[t][3] + bv) << 16);
    } else if (mode == 1) {
#pragma unroll
      for (int j = 0; j < 4; ++j) {
        const int row = mt * 16 + kb * 4 + j;
        X[row * 132 + col] += acc[t][j] + bv;
      }
    } else {
#pragma unroll
      for (int j = 0; j < 4; ++j) {
        const int row = mt * 16 + kb * 4 + j;
        float val = acc[t][j] + bv;
        if (mode == 2) val = fmaxf(val, 0.f);
        OUTp[row * 256 + ((co + col) ^ ((row & 7) << 3))] = (u16)f2bfu(val);
      }
    }
  }
}

__global__ __launch_bounds__(256, 2) void k_xform(
    const float* __restrict__ feat, const float* __restrict__ featT, const int useT,
    const float4* __restrict__ xyzw, const int* __restrict__ knn,
    const float* __restrict__ wf, const float* __restrict__ wp,
    const u16* __restrict__ wb, float* __restrict__ out) {
  __shared__ __align__(16) float sm[12544];
  float* X   = sm;                       // [32][132] f32 residual
  u16* ZH    = (u16*)(sm + 4224);        // [32][128] bf16: z / h / P(4x1024)
  u16* QKp   = (u16*)(sm + 6272);        // [32][256] bf16: Q,K / attn-out / ff1-out
  u16* Vtp   = (u16*)(sm + 10368);       // [128][32] bf16: V transposed
  float4* GX = (float4*)(sm + 12416);    // [32]
  const int g = blockIdx.x, b = g >> 10, tid = threadIdx.x;
  const int r = tid >> 3, sub = tid & 7, cs = sub * 16;
  const int n = knn[g * 32 + r];
  if (tid < 32) GX[tid] = xyzw[(size_t)b * 4096 + knn[g * 32 + tid]];
  if (useT) {
    const f32x4* srcp = (const f32x4*)(featT + ((size_t)(b * 4096 + n)) * 128 + cs);
    float* dst = &X[r * 132 + cs];
#pragma unroll
    for (int j = 0; j < 4; ++j)
      *(f32x4*)&dst[j * 4] = __builtin_nontemporal_load(&srcp[j]);
  } else {
    const size_t fb0 = (size_t)b * 524288 + n;
    float* dst = &X[r * 132 + cs];
#pragma unroll
    for (int j = 0; j < 16; ++j)
      dst[j] = __builtin_nontemporal_load(&feat[fb0 + (size_t)(cs + j) * 4096]);
  }
  __syncthreads();
  // h = relu(bn(gxyz @ w1.T + b1)) -> ZH bf16 (cols 0..63, swizzled)
  {
    const float4 g4 = GX[r];
    const float rs = 1.0f / sqrtf(1.0f + 1e-5f);
    const int mask = (r & 7) << 3;
#pragma unroll
    for (int i = 0; i < 4; ++i) {
      u32 wpk = 0;
#pragma unroll
      for (int e = 0; e < 2; ++e) {
        const int c = sub * 8 + 2 * i + e;
        float hv = g4.x * wf[W_PEW1 + c * 3] + g4.y * wf[W_PEW1 + c * 3 + 1] +
                   g4.z * wf[W_PEW1 + c * 3 + 2] + wf[W_PEB1 + c];
        hv = hv * (wf[W_BNG + c] * rs) + wf[W_BNB + c];
        hv = fmaxf(hv, 0.f);
        wpk |= f2bfu(hv) << (16 * e);
      }
      *(u32*)&ZH[r * 128 + ((sub * 8 + 2 * i) ^ mask)] = wpk;
    }
  }
  __syncthreads();
  // X += h @ w2.T + b2
  gemmR(ZH, 128, wb + WB_P2, 64, wf + W_PEB2, X, QKp, 0, Vtp, 1, tid);
  __syncthreads();
#pragma unroll 1
  for (int l = 0; l < 2; ++l) {
    ln_z(X, ZH, tid);
    __syncthreads();
#pragma unroll 1
    for (int i = 0; i < 3; ++i)
      gemmR(ZH, 128, wb + WB_Q + l * 49152 + i * 16384, 128,
            wp + WP_QB + l * 384 + i * 128, X, QKp,
            (i == 1) ? 128 : 0, Vtp, (i == 2) ? 3 : 0, tid);
    __syncthreads();
    // ---- attention: one head per wave, all-MFMA ----
    {
      const int wv = tid >> 6, wl = tid & 63;
      const int hh = wv, lm = wl & 15, kb = wl >> 4;
      bf16x8 qf[2], kf[2];
#pragma unroll
      for (int t = 0; t < 2; ++t) {
        const int rr = t * 16 + lm;
        const int msk = (rr & 7) << 3;
        qf[t] = *(const bf16x8*)&QKp[rr * 256 + ((hh * 32 + kb * 8) ^ msk)];
        kf[t] = *(const bf16x8*)&QKp[rr * 256 + ((128 + hh * 32 + kb * 8) ^ msk)];
      }
      const f32x4 zz = {0.f, 0.f, 0.f, 0.f};
      f32x4 sc[2][2];
      sc[0][0] = MFMA(qf[0], kf[0], zz); sc[0][1] = MFMA(qf[0], kf[1], zz);
      sc[1][0] = MFMA(qf[1], kf[0], zz); sc[1][1] = MFMA(qf[1], kf[1], zz);
      const float scale = 0.1767766952966369f;  // 1/sqrt(32)
      u16* Pp = ZH + hh * 1024;
#pragma unroll
      for (int mtl = 0; mtl < 2; ++mtl) {
#pragma unroll
        for (int j = 0; j < 4; ++j) {
          float a0 = sc[mtl][0][j] * scale, a1 = sc[mtl][1][j] * scale;
          float mx = fmaxf(a0, a1);
          mx = fmaxf(mx, __shfl_xor(mx, 1));
          mx = fmaxf(mx, __shfl_xor(mx, 2));
          mx = fmaxf(mx, __shfl_xor(mx, 4));
          mx = fmaxf(mx, __shfl_xor(mx, 8));
          const float e0 = __expf(a0 - mx), e1 = __expf(a1 - mx);
          float sum = e0 + e1;
          sum += __shfl_xor(sum, 1); sum += __shfl_xor(sum, 2);
          sum += __shfl_xor(sum, 4); sum += __shfl_xor(sum, 8);
          const float inv = 1.0f / sum;
          const int q2 = mtl * 16 + kb * 4 + j;
          const int qm = (q2 & 3) << 3;
          Pp[q2 * 32 + (lm ^ qm)]        = (u16)f2bfu(e0 * inv);
          Pp[q2 * 32 + ((16 + lm) ^ qm)] = (u16)f2bfu(e1 * inv);
        }
      }
      __syncthreads();  // P visible
      bf16x8 pf[2], vf[2];
#pragma unroll
      for (int t = 0; t < 2; ++t) {
        const int q2 = t * 16 + lm;
        pf[t] = *(const bf16x8*)&Pp[q2 * 32 + ((kb * 8) ^ ((q2 & 3) << 3))];
        const int d = hh * 32 + t * 16 + lm;
        vf[t] = *(const bf16x8*)&Vtp[d * 32 + ((kb * 8) ^ ((d & 3) << 3))];
      }
      f32x4 av[2][2];
      av[0][0] = MFMA(pf[0], vf[0], zz); av[0][1] = MFMA(pf[0], vf[1], zz);
      av[1][0] = MFMA(pf[1], vf[0], zz); av[1][1] = MFMA(pf[1], vf[1], zz);
#pragma unroll
      for (int mtl = 0; mtl < 2; ++mtl)
#pragma unroll
        for (int ntl = 0; ntl < 2; ++ntl)
#pragma unroll
          for (int j = 0; j < 4; ++j) {
            const int row = mtl * 16 + kb * 4 + j;
            const int col = hh * 32 + ntl * 16 + lm;
            QKp[row * 256 + (col ^ ((row & 7) << 3))] = (u16)f2bfu(av[mtl][ntl][j]);
          }
    }
    __syncthreads();
    gemmR(QKp, 256, wb + WB_O + l * 16384, 128, wf + W_OUTB + l * 128,
          X, QKp, 0, Vtp, 1, tid);
    __syncthreads();
    ln_z(X, ZH, tid);
    __syncthreads();
#pragma unroll 1
    for (int i = 0; i < 2; ++i)
      gemmR(ZH, 128, wb + WB_F1 + l * 32768 + i * 16384, 128,
            wp + WP_FB + l * 256 + i * 128, X, QKp, i * 128, Vtp, 2, tid);
    __syncthreads();
    gemmR(QKp, 256, wb + WB_F2 + l * 32768, 256, wf + W_FF2B + l * 128,
          X, QKp, 0, Vtp, 1, tid);
    __syncthreads();
  }
  // pool -> ZH (as f32)
  float* pooled = (float*)ZH;
  if (tid < 128) {
    float m = X[tid];
#pragma unroll
    for (int rr = 1; rr < 32; ++rr) m = fmaxf(m, X[rr * 132 + tid]);
    pooled[tid] = m;
  }
  __syncthreads();
  // fc
  {
    float acc = wf[W_FCB + tid];
    const float* wr = wf + W_FCW + tid * 128;
#pragma unroll 8
    for (int c = 0; c < 128; c += 4) {
      float4 w4 = *(const float4*)&wr[c];
      float4 x4 = *(const float4*)&pooled[c];
      acc += dot4(x4, w4);
    }
    const int s = g & 1023;
    __builtin_nontemporal_store(acc,
        &out[24576 + (size_t)b * 262144 + (size_t)tid * 1024 + s]);
  }
}

extern "C" void kernel_launch(void* const* d_in, const int* in_sizes, int n_in,
                              void* d_out, int out_size, void* d_ws, size_t ws_size,
                              hipStream_t stream) {
  (void)in_sizes; (void)n_in; (void)out_size;
  char* ws = (char*)d_ws;
  float* wf    = (float*)ws;
  float4* xyzw = (float4*)(ws + OFF_XYZW);
  float4* newx = (float4*)(ws + OFF_NEWX);
  int* knni    = (int*)(ws + OFF_KNN);
  float* wp    = (float*)(ws + OFF_WP);
  u16* wb      = (u16*)(ws + OFF_WB);
  const float* xyz  = (const float*)d_in[0];
  const float* feat = (const float*)d_in[1];
  const int useT = (ws_size >= END_BIG) ? 1 : 0;
  float* featT = useT ? (float*)(ws + OFF_FEATT) : (float*)d_in[1];
  WArgs wa;
  for (int i = 0; i < 20; ++i) wa.p[i] = (const float*)d_in[2 + i];
  float* outp = (float*)d_out;

  hipLaunchKernelGGL(k_setup, dim3(1334), dim3(256), 0, stream, wa, wf, wp, wb, xyz, xyzw);
  hipLaunchKernelGGL(k_pre, dim3(useT ? 4104 : 8), dim3(256), 0, stream,
                     xyzw, newx, outp, feat, featT);
  hipLaunchKernelGGL(k_knn, dim3(2048), dim3(128), 0, stream, xyzw, newx, knni);
  hipLaunchKernelGGL(k_xform, dim3(8192), dim3(256), 0, stream,
                     feat, featT, useT, xyzw, knni, wf, wp, wb, outp);
}